// Round 9
// baseline (1872.120 us; speedup 1.0000x reference)
//
#include <hip/hip_runtime.h>
#include <hip/hip_bf16.h>
#include <math.h>

typedef __bf16 bf16x8 __attribute__((ext_vector_type(8)));
typedef float floatx4 __attribute__((ext_vector_type(4)));

#define T_LEN 128

// ws layout: bf16 fragment-packed weights, gates KI-MAJOR:
//   gate frag addr = WP_OFF + ki*65536 + ct*1024 + lane*16
// Gate K order: [ h(0..255) | z(256..287) | a(288..295) | pad(296..319) ]
//   ki0..7 = h, ki8 = z, ki9 = a+pad   (R6's verified prep layout)
#define WP_OFF   0
#define WP_SZ    (64*10*64*16)     // 655360
#define W1P_OFF  (WP_OFF + WP_SZ)
#define W1P_SZ   (8*8*64*16)       // 65536
#define W2P_OFF  (W1P_OFF + W1P_SZ)
#define W2P_SZ   (8*4*64*16)       // 32768
#define WZP_OFF  (W2P_OFF + W2P_SZ)
#define WZP_SZ   (4*4*64*16)       // 16384
#define WS_NEEDED ((size_t)(WZP_OFF + WZP_SZ))   // 770048 B

// s_waitcnt imm: wait until <=N vmem outstanding (expcnt/lgkmcnt don't care)
#define WAITVM(N) (((N) & 0xF) | (0x7 << 4) | (0xF << 8) | (((N) >> 4) << 14))

// raw barrier: LDS writes visible, VMEM (DMA) loads STAY IN FLIGHT
#define BAR() do {                                                  \
    asm volatile("s_waitcnt lgkmcnt(0)" ::: "memory");              \
    __builtin_amdgcn_sched_barrier(0);                              \
    __builtin_amdgcn_s_barrier();                                   \
    __builtin_amdgcn_sched_barrier(0);                              \
} while (0)

// ---- fast transcendentals ------------------------------------------------
#if __has_builtin(__builtin_amdgcn_exp2f)
#define EXP2F(x) __builtin_amdgcn_exp2f(x)
#else
#define EXP2F(x) exp2f(x)
#endif
#if __has_builtin(__builtin_amdgcn_logf)
#define LOG2F(x) __builtin_amdgcn_logf(x)
#else
#define LOG2F(x) log2f(x)
#endif
#if __has_builtin(__builtin_amdgcn_rcpf)
#define RCPF(x) __builtin_amdgcn_rcpf(x)
#else
#define RCPF(x) (1.0f/(x))
#endif

__device__ __forceinline__ float fsigmoid(float x) {
    return RCPF(1.0f + EXP2F(-1.4426950408889634f * x));
}
__device__ __forceinline__ float ftanh(float x) {
    return 1.0f - 2.0f * RCPF(1.0f + EXP2F(2.8853900817779268f * x));
}

// async 16B/lane global->LDS DMA; LDS base wave-uniform, lands at +lane*16
__device__ __forceinline__ void dma16(const void* g, void* lds) {
    __builtin_amdgcn_global_load_lds(
        (const __attribute__((address_space(1))) void*)g,
        (__attribute__((address_space(3))) void*)lds,
        16, 0, 0);
}

// ---------------- prep: f32 weights -> bf16 B-fragment-linear in ws -------
// Gate K remap (R6-verified): k<256 -> h (Whh col k); 256<=k<288 -> z
// (Wih col 8+(k-256)); 288<=k<296 -> a (Wih col k-288); else 0.
__global__ void prep_kernel(const float* __restrict__ Wih, const float* __restrict__ Whh,
                            const float* __restrict__ W1,  const float* __restrict__ W2,
                            const float* __restrict__ Wz,  unsigned char* __restrict__ ws)
{
    int id = blockIdx.x * blockDim.x + threadIdx.x;
    __bf16* Wp  = (__bf16*)(ws + WP_OFF);
    __bf16* W1p = (__bf16*)(ws + W1P_OFF);
    __bf16* W2p = (__bf16*)(ws + W2P_OFF);
    __bf16* Wzp = (__bf16*)(ws + WZP_OFF);
    if (id < 40960) {                       // gates: 64 ct x 10 ki x 64 lanes
        int ct = id / 640, rem = id % 640;
        int ki = rem / 64, lane = rem % 64;
        int row = ct * 16 + (lane & 15);                 // gate-output col
        int kb  = ki * 32 + (lane >> 4) * 8;
        for (int j = 0; j < 8; ++j) {
            int k = kb + j;
            float v;
            if (k < 256)      v = Whh[row * 256 + k];            // h block
            else if (k < 288) v = Wih[row * 40 + 8 + (k - 256)]; // z block
            else if (k < 296) v = Wih[row * 40 + (k - 288)];     // a block
            else              v = 0.0f;                          // pad
            Wp[((size_t)(ki * 64 + ct) * 64 + lane) * 8 + j] = (__bf16)v;
        }
    } else if (id < 45056) {                // W1: 8 ct x 8 ki (ct-major)
        int id2 = id - 40960;
        int rem = id2 % 512, lane = rem % 64;
        int row = (id2 / 512) * 16 + (lane & 15);
        int kb  = (rem / 64) * 32 + (lane >> 4) * 8;
        for (int j = 0; j < 8; ++j) W1p[(size_t)id2 * 8 + j] = (__bf16)W1[row * 256 + kb + j];
    } else if (id < 47104) {                // W2: 8 ct x 4 ki
        int id3 = id - 45056;
        int rem = id3 % 256, lane = rem % 64;
        int row = (id3 / 256) * 16 + (lane & 15);
        int kb  = (rem / 64) * 32 + (lane >> 4) * 8;
        for (int j = 0; j < 8; ++j) W2p[(size_t)id3 * 8 + j] = (__bf16)W2[row * 128 + kb + j];
    } else if (id < 48128) {                // Wz: 4 ct x 4 ki
        int id4 = id - 47104;
        int rem = id4 % 256, lane = rem % 64;
        int row = (id4 / 256) * 16 + (lane & 15);
        int kb  = (rem / 64) * 32 + (lane >> 4) * 8;
        for (int j = 0; j < 8; ++j) Wzp[(size_t)id4 * 8 + j] = (__bf16)Wz[row * 128 + kb + j];
    }
}

// ---------------- fast path: 64 blocks x 1024 threads (16 waves) ----------
// R9 = R8's DMA-ring gates + R6's gates||MLP wave split.
//  Waves 0-7  (gate): stream gates-h,a(t) [ki0..7,9] via slots ring during
//    interval 1 (exact vmcnt(4) waits, never drained); after B_z: ki8 (z)
//    + LSTM cell -> h(t) into xh[nb]. Zero VGPR cost for weights.
//  Waves 8-15 (MLP): concurrently compute z(t-1)=MLP(h(t-1)) from xh[cb]:
//    u1 (W1 VGPR-resident) -> u2 (W2 LDS) -> zz (Wz LDS) -> softplus ->
//    z into xh[cb] z-cols + out store. Intra-MLP order via monotonic LDS
//    counters (R6-verified). 2 raw barriers/step.
// xh cols: [ h(0..255) | z(256..287) | a(288..295) | pad(..319) ]
__global__ __launch_bounds__(1024) void seq_mfma(
    const float* __restrict__ A,   const float* __restrict__ eps,
    const float* __restrict__ z0,  const float* __restrict__ h0,
    const float* __restrict__ c0,
    const float* __restrict__ bih, const float* __restrict__ bhh,
    const float* __restrict__ b1,  const float* __restrict__ b2,
    const float* __restrict__ bz,
    const unsigned char* __restrict__ ws, float* __restrict__ out)
{
    const int tid  = threadIdx.x;
    const int wave = tid >> 6;
    const int lane = tid & 63;
    const int lrow = lane & 15;
    const int quad = lane >> 4;
    const int n0   = blockIdx.x * 16;

    __shared__ __align__(16) __bf16 slots[8][2][2048];   // 64 KB DMA rings
    __shared__ __align__(16) __bf16 wmlp2[(W2P_SZ + WZP_SZ) / 2];  // 48 KB
    __shared__ __align__(16) __bf16 xh[2][16][328];      // 20.5 KB
    __shared__ __align__(16) __bf16 u1s[16][136];
    __shared__ __align__(16) __bf16 u2s[16][136];
    __shared__ int c1s, c2s;

    const char* wsb = (const char*)ws;

    // one-time: W2|Wz global -> LDS (3072 x 16B)
    {
        const float4* src = (const float4*)(wsb + W2P_OFF);
        float4* dst = (float4*)wmlp2;
        for (int i = tid; i < 3072; i += 1024) dst[i] = src[i];
    }
    // init both xh buffers: h0 | z0 | a=0 | pad 0
    for (int idx = tid; idx < 2 * 16 * 320; idx += 1024) {
        int b = idx / (16 * 320);
        int rem = idx % (16 * 320);
        int r = rem / 320, col = rem % 320;
        float v;
        if (col < 256)      v = h0[col];
        else if (col < 288) v = z0[col - 256];
        else                v = 0.0f;
        xh[b][r][col] = (__bf16)v;
    }
    if (tid < 128)   // a(t=0)
        xh[0][tid >> 3][288 + (tid & 7)] =
            (__bf16)A[((size_t)(n0 + (tid >> 3)) * T_LEN + 0) * 8 + (tid & 7)];
    if (tid == 0) { c1s = 0; c2s = 0; }
    __syncthreads();   // the only draining barrier (init once)

    if (wave < 8) {
        // ======================= GATE WAVES =======================
        const int w = wave;

        float gb[4][2];
        #pragma unroll
        for (int g = 0; g < 4; ++g)
            #pragma unroll
            for (int j = 0; j < 2; ++j) {
                int unit = 32 * w + 16 * j + lrow;
                gb[g][j] = bih[g * 256 + unit] + bhh[g * 256 + unit];
            }
        float cst[2][4];
        #pragma unroll
        for (int j = 0; j < 2; ++j) {
            float cv = c0[32 * w + 16 * j + lrow];
            #pragma unroll
            for (int r = 0; r < 4; ++r) cst[j][r] = cv;
        }

        #define ISSUEHALF(KI, H) do {                                             \
            _Pragma("unroll")                                                     \
            for (int gg = 0; gg < 2; ++gg)                                        \
                _Pragma("unroll")                                                 \
                for (int j = 0; j < 2; ++j)                                       \
                    dma16(wsb + WP_OFF + (size_t)(KI) * 65536 +                   \
                          ((size_t)((2 * (H) + gg) * 16 + 2 * w + j) * 1024) +    \
                          (size_t)lane * 16,                                      \
                          (void*)&slots[w][H][(gg * 2 + j) * 512]);               \
        } while (0)
        #define GHALF(H, NKI, DOREF) do {                                         \
            __builtin_amdgcn_s_waitcnt(WAITVM(4));                                \
            __builtin_amdgcn_sched_barrier(0);                                    \
            _Pragma("unroll")                                                     \
            for (int gg = 0; gg < 2; ++gg)                                        \
                _Pragma("unroll")                                                 \
                for (int j = 0; j < 2; ++j) {                                     \
                    bf16x8 b_ = *(const bf16x8*)&slots[w][H][(gg * 2 + j) * 512   \
                                                             + lane * 8];         \
                    acc[2 * (H) + gg][j] = __builtin_amdgcn_mfma_f32_16x16x32_bf16( \
                        af, b_, acc[2 * (H) + gg][j], 0, 0, 0);                   \
                }                                                                 \
            __builtin_amdgcn_sched_barrier(0);                                    \
            if (DOREF) ISSUEHALF(NKI, H);                                         \
        } while (0)
        #define GKI(KI, NKI) do {                                                 \
            bf16x8 af = *(const bf16x8*)&xh[cb][lrow][(KI) * 32 + quad * 8];      \
            GHALF(0, NKI, 1);                                                     \
            GHALF(1, NKI, 1);                                                     \
        } while (0)

        // prologue: prefetch ki0 both halves (8 ops in flight entering loop)
        ISSUEHALF(0, 0);
        ISSUEHALF(0, 1);

        for (int t = 0; t < T_LEN; ++t) {
            const int cb = t & 1;
            const int nb = cb ^ 1;

            floatx4 acc[4][2];
            #pragma unroll
            for (int g = 0; g < 4; ++g)
                #pragma unroll
                for (int j = 0; j < 2; ++j)
                    acc[g][j] = (floatx4){gb[g][j], gb[g][j], gb[g][j], gb[g][j]};

            // interval 1: h slabs 0..7 then a slab 9; ring refills 1 ki ahead
            GKI(0, 1); GKI(1, 2); GKI(2, 3); GKI(3, 4);
            GKI(4, 5); GKI(5, 6); GKI(6, 7); GKI(7, 9);
            GKI(9, 8);          // a-slab; refills ki8 (z) — lands across B_z

            BAR();   // B_z: z(t-1) staged in xh[cb] by MLP waves

            // interval 2: z slab (ki8) + cell
            {
                bf16x8 af = *(const bf16x8*)&xh[cb][lrow][8 * 32 + quad * 8];
                if (t + 1 < T_LEN) {
                    GHALF(0, 0, 1);   // refill next-step ki0 H0
                    GHALF(1, 0, 1);   // refill next-step ki0 H1
                } else {
                    GHALF(0, 0, 0);
                    __builtin_amdgcn_s_waitcnt(WAITVM(0));
                    __builtin_amdgcn_sched_barrier(0);
                    #pragma unroll
                    for (int gg = 0; gg < 2; ++gg)
                        #pragma unroll
                        for (int j = 0; j < 2; ++j) {
                            bf16x8 b_ = *(const bf16x8*)&slots[w][1][(gg * 2 + j) * 512
                                                                     + lane * 8];
                            acc[2 + gg][j] = __builtin_amdgcn_mfma_f32_16x16x32_bf16(
                                af, b_, acc[2 + gg][j], 0, 0, 0);
                        }
                }
            }
            // LSTM cell -> h(t) into xh[nb] (h cols at offset 0)
            #pragma unroll
            for (int j = 0; j < 2; ++j)
                #pragma unroll
                for (int r = 0; r < 4; ++r) {
                    float iv = fsigmoid(acc[0][j][r]);
                    float fv = fsigmoid(acc[1][j][r]);
                    float gv = ftanh(acc[2][j][r]);
                    float ov = fsigmoid(acc[3][j][r]);
                    float cn = fv * cst[j][r] + iv * gv;
                    cst[j][r] = cn;
                    xh[nb][quad * 4 + r][32 * w + 16 * j + lrow] = (__bf16)(ov * ftanh(cn));
                }

            BAR();   // B_h: h(t) + a(t+1) staged in xh[nb]
        }
        #undef GKI
        #undef GHALF
        #undef ISSUEHALF
        return;   // MLP waves run the z(127) epilogue alone (no barriers there)
    }

    // ======================= MLP WAVES =======================
    const int w2 = wave - 8;
    const __bf16* w2l = wmlp2;            // ct*2048 + ki*512 + lane*8
    const __bf16* wzl = wmlp2 + 16384;    // ct*2048 + ki*512 + lane*8

    // W1 VGPR-resident (ct = w2): 32 regs
    bf16x8 w1f[8];
    #pragma unroll
    for (int k = 0; k < 8; ++k)
        w1f[k] = *(const bf16x8*)(wsb + W1P_OFF + ((size_t)(w2 * 8 + k) * 64 + lane) * 16);

    float u1b = b1[w2 * 16 + lrow];
    float u2b = b2[w2 * 16 + lrow];
    float bzl = bz[(w2 & 1) * 16 + lrow];
    float bzr = bz[32 + (w2 & 1) * 16 + lrow];
    float epsr[4] = {0, 0, 0, 0};

    // body at step TE computes z(TE-1) from h(TE-1) in xh[CBUF]
    #define MLP_BODY(CBUF, TE) do {                                               \
        floatx4 a1 = (floatx4){u1b, u1b, u1b, u1b};                               \
        _Pragma("unroll")                                                         \
        for (int ki = 0; ki < 8; ++ki) {                                          \
            bf16x8 af = *(const bf16x8*)&xh[CBUF][lrow][ki * 32 + quad * 8];      \
            a1 = __builtin_amdgcn_mfma_f32_16x16x32_bf16(af, w1f[ki], a1, 0, 0, 0); \
        }                                                                         \
        _Pragma("unroll")                                                         \
        for (int r = 0; r < 4; ++r)                                               \
            u1s[quad * 4 + r][w2 * 16 + lrow] = (__bf16)fmaxf(a1[r], 0.0f);       \
        asm volatile("s_waitcnt lgkmcnt(0)" ::: "memory");                        \
        __builtin_amdgcn_sched_barrier(0);                                        \
        if (lane == 0) atomicAdd(&c1s, 1);                                        \
        while (*(volatile int*)&c1s < 8 * (TE)) __builtin_amdgcn_s_sleep(1);      \
        __builtin_amdgcn_sched_barrier(0);                                        \
        floatx4 a2 = (floatx4){u2b, u2b, u2b, u2b};                               \
        _Pragma("unroll")                                                         \
        for (int ki = 0; ki < 4; ++ki) {                                          \
            bf16x8 af = *(const bf16x8*)&u1s[lrow][ki * 32 + quad * 8];           \
            bf16x8 bb = *(const bf16x8*)&w2l[w2 * 2048 + ki * 512 + lane * 8];    \
            a2 = __builtin_amdgcn_mfma_f32_16x16x32_bf16(af, bb, a2, 0, 0, 0);    \
        }                                                                         \
        _Pragma("unroll")                                                         \
        for (int r = 0; r < 4; ++r)                                               \
            u2s[quad * 4 + r][w2 * 16 + lrow] = (__bf16)fmaxf(a2[r], 0.0f);       \
        asm volatile("s_waitcnt lgkmcnt(0)" ::: "memory");                        \
        __builtin_amdgcn_sched_barrier(0);                                        \
        if (lane == 0) atomicAdd(&c2s, 1);                                        \
        if (w2 < 2) {                                                             \
            while (*(volatile int*)&c2s < 8 * (TE)) __builtin_amdgcn_s_sleep(1);  \
            __builtin_amdgcn_sched_barrier(0);                                    \
            floatx4 aL = (floatx4){bzl, bzl, bzl, bzl};                           \
            floatx4 aR = (floatx4){bzr, bzr, bzr, bzr};                           \
            _Pragma("unroll")                                                     \
            for (int ki = 0; ki < 4; ++ki) {                                      \
                bf16x8 af = *(const bf16x8*)&u2s[lrow][ki * 32 + quad * 8];       \
                bf16x8 bl = *(const bf16x8*)&wzl[(w2)     * 2048 + ki * 512 + lane * 8]; \
                bf16x8 br = *(const bf16x8*)&wzl[(w2 + 2) * 2048 + ki * 512 + lane * 8]; \
                aL = __builtin_amdgcn_mfma_f32_16x16x32_bf16(af, bl, aL, 0, 0, 0); \
                aR = __builtin_amdgcn_mfma_f32_16x16x32_bf16(af, br, aR, 0, 0, 0); \
            }                                                                     \
            _Pragma("unroll")                                                     \
            for (int r = 0; r < 4; ++r) {                                         \
                float raw = aR[r];                                                \
                float sp  = (raw > 20.0f)                                         \
                          ? raw                                                   \
                          : 0.6931471805599453f *                                 \
                            LOG2F(1.0f + EXP2F(1.4426950408889634f * raw));       \
                float zv  = aL[r] + sp * epsr[r];                                 \
                xh[CBUF][quad * 4 + r][256 + w2 * 16 + lrow] = (__bf16)zv;        \
                out[((size_t)(n0 + quad * 4 + r) * T_LEN + ((TE) - 1)) * 32       \
                    + w2 * 16 + lrow] = zv;                                       \
            }                                                                     \
        }                                                                         \
    } while (0)

    for (int t = 0; t < T_LEN; ++t) {
        const int cb = t & 1;
        const int nb = cb ^ 1;

        // a(t+1) prefetch issued early (hidden under MLP body / gate stream)
        float a_nxt = 0.0f;
        const int atid = (w2 - 2) * 64 + lane;   // valid for w2==2,3
        if ((w2 == 2 || w2 == 3) && t + 1 < T_LEN)
            a_nxt = A[((size_t)(n0 + (atid >> 3)) * T_LEN + (t + 1)) * 8 + (atid & 7)];

        // interval 1: z(t-1) = MLP(h(t-1)), concurrent with gates-h(t)
        if (t > 0)
            MLP_BODY(cb, t);

        BAR();   // B_z

        // interval 2 (light): eps(t) prefetch, a(t+1) stage
        if (w2 < 2) {
            #pragma unroll
            for (int r = 0; r < 4; ++r)
                epsr[r] = eps[((size_t)(n0 + quad * 4 + r) * T_LEN + t) * 32
                              + w2 * 16 + lrow];
        }
        if ((w2 == 2 || w2 == 3) && t + 1 < T_LEN)
            xh[nb][atid >> 3][288 + (atid & 7)] = (__bf16)a_nxt;

        BAR();   // B_h
    }

    // epilogue: z(127) from h(127) (in xh[0]); no barriers, gate waves exited
    MLP_BODY(0, T_LEN);
    #undef MLP_BODY
}

// ---------------- fallback: proven R4 VALU kernel (f32 hard-coded) --------
struct SM {
    float zx[4][40]; float h[4][256]; float u1[4][128]; float u2[4][128]; float zz[4][64];
};

__global__ __launch_bounds__(256) void seq_valu(
    const float* __restrict__ A, const float* __restrict__ eps,
    const float* __restrict__ z0, const float* __restrict__ h0, const float* __restrict__ c0,
    const float* __restrict__ Wih, const float* __restrict__ Whh,
    const float* __restrict__ bih, const float* __restrict__ bhh,
    const float* __restrict__ W1, const float* __restrict__ b1,
    const float* __restrict__ W2, const float* __restrict__ b2,
    const float* __restrict__ Wz, const float* __restrict__ bz, float* __restrict__ out)
{
    __shared__ SM sm;
    const int tid = threadIdx.x;
    const int n0  = blockIdx.x * 4;
    if (tid < 128) { int rr = tid >> 5, cc = tid & 31; sm.zx[rr][8 + cc] = z0[cc]; }
    for (int i = tid; i < 4 * 256; i += 256) sm.h[i >> 8][i & 255] = h0[i & 255];
    float c[4];
    #pragma unroll
    for (int rr = 0; rr < 4; ++rr) c[rr] = c0[tid];
    float gbias[4];
    #pragma unroll
    for (int g = 0; g < 4; ++g) gbias[g] = bih[g * 256 + tid] + bhh[g * 256 + tid];

    for (int t = 0; t < T_LEN; ++t) {
        if (tid < 32) { int rr = tid >> 3, cc = tid & 7;
            sm.zx[rr][cc] = A[((size_t)(n0 + rr) * T_LEN + t) * 8 + cc]; }
        __syncthreads();
        float acc[4][4];
        #pragma unroll
        for (int g = 0; g < 4; ++g)
            #pragma unroll
            for (int rr = 0; rr < 4; ++rr) acc[g][rr] = gbias[g];
        for (int k = 0; k < 40; ++k) {
            float xv[4];
            #pragma unroll
            for (int rr = 0; rr < 4; ++rr) xv[rr] = sm.zx[rr][k];
            #pragma unroll
            for (int g = 0; g < 4; ++g) {
                float w = Wih[(size_t)(g * 256 + tid) * 40 + k];
                #pragma unroll
                for (int rr = 0; rr < 4; ++rr) acc[g][rr] += w * xv[rr];
            }
        }
        for (int k = 0; k < 256; ++k) {
            float hv[4];
            #pragma unroll
            for (int rr = 0; rr < 4; ++rr) hv[rr] = sm.h[rr][k];
            #pragma unroll
            for (int g = 0; g < 4; ++g) {
                float w = Whh[(size_t)(g * 256 + tid) * 256 + k];
                #pragma unroll
                for (int rr = 0; rr < 4; ++rr) acc[g][rr] += w * hv[rr];
            }
        }
        __syncthreads();
        #pragma unroll
        for (int rr = 0; rr < 4; ++rr) {
            float iv = 1.0f / (1.0f + expf(-acc[0][rr]));
            float fv = 1.0f / (1.0f + expf(-acc[1][rr]));
            float gv = tanhf(acc[2][rr]);
            float ov = 1.0f / (1.0f + expf(-acc[3][rr]));
            float cn = fv * c[rr] + iv * gv;
            c[rr] = cn;
            sm.h[rr][tid] = ov * tanhf(cn);
        }
        __syncthreads();
        { int col = tid & 127, rb = (tid >> 7) * 2;
          float a0 = b1[col], a1 = a0;
          for (int k = 0; k < 256; ++k) { float w = W1[(size_t)col * 256 + k];
              a0 += w * sm.h[rb][k]; a1 += w * sm.h[rb + 1][k]; }
          sm.u1[rb][col] = fmaxf(a0, 0.0f); sm.u1[rb + 1][col] = fmaxf(a1, 0.0f); }
        __syncthreads();
        { int col = tid & 127, rb = (tid >> 7) * 2;
          float a0 = b2[col], a1 = a0;
          for (int k = 0; k < 128; ++k) { float w = W2[(size_t)col * 128 + k];
              a0 += w * sm.u1[rb][k]; a1 += w * sm.u1[rb + 1][k]; }
          sm.u2[rb][col] = fmaxf(a0, 0.0f); sm.u2[rb + 1][col] = fmaxf(a1, 0.0f); }
        __syncthreads();
        { int rr = tid >> 6, col = tid & 63;
          float a0 = bz[col];
          for (int k = 0; k < 128; ++k) a0 += Wz[(size_t)col * 128 + k] * sm.u2[rr][k];
          sm.zz[rr][col] = a0; }
        __syncthreads();
        if (tid < 128) {
            int rr = tid >> 5, cc = tid & 31;
            float loc = sm.zz[rr][cc], raw = sm.zz[rr][cc + 32];
            float sp  = (raw > 20.0f) ? raw : log1pf(expf(raw));
            float ev  = eps[((size_t)(n0 + rr) * T_LEN + t) * 32 + cc];
            float zv  = loc + sp * ev;
            sm.zx[rr][8 + cc] = zv;
            out[((size_t)(n0 + rr) * T_LEN + t) * 32 + cc] = zv;
        }
        __syncthreads();
    }
}

extern "C" void kernel_launch(void* const* d_in, const int* in_sizes, int n_in,
                              void* d_out, int out_size, void* d_ws, size_t ws_size,
                              hipStream_t stream)
{
    const float* A   = (const float*)d_in[0];
    const float* eps = (const float*)d_in[1];
    const float* z0  = (const float*)d_in[2];
    const float* h0  = (const float*)d_in[3];
    const float* c0  = (const float*)d_in[4];
    const float* Wih = (const float*)d_in[5];
    const float* Whh = (const float*)d_in[6];
    const float* bih = (const float*)d_in[7];
    const float* bhh = (const float*)d_in[8];
    const float* W1  = (const float*)d_in[9];
    const float* b1  = (const float*)d_in[10];
    const float* W2  = (const float*)d_in[11];
    const float* b2  = (const float*)d_in[12];
    const float* Wz  = (const float*)d_in[13];
    const float* bz  = (const float*)d_in[14];
    float* out = (float*)d_out;

    if (ws_size >= WS_NEEDED) {
        prep_kernel<<<188, 256, 0, stream>>>(Wih, Whh, W1, W2, Wz, (unsigned char*)d_ws);
        seq_mfma<<<64, 1024, 0, stream>>>(A, eps, z0, h0, c0,
                                          bih, bhh, b1, b2, bz,
                                          (const unsigned char*)d_ws, out);
    } else {
        seq_valu<<<256, 256, 0, stream>>>(A, eps, z0, h0, c0, Wih, Whh, bih, bhh,
                                          W1, b1, W2, b2, Wz, bz, out);
    }
}

// Round 10
// 1598.616 us; speedup vs baseline: 1.1711x; 1.1711x over previous
//
#include <hip/hip_runtime.h>
#include <hip/hip_bf16.h>
#include <math.h>

typedef __bf16 bf16x8 __attribute__((ext_vector_type(8)));
typedef float floatx4 __attribute__((ext_vector_type(4)));

#define T_LEN 128

// ws layout: bf16 fragment-packed weights, gates KI-MAJOR:
//   gate frag addr = WP_OFF + ki*65536 + ct*1024 + lane*16
// Gate K order: [ h(0..255) | z(256..287) | a(288..295) | pad(296..319) ]
//   ki0..7 = h, ki8 = z, ki9 = a+pad   (R6/R9's verified prep layout)
#define WP_OFF   0
#define WP_SZ    (64*10*64*16)     // 655360
#define W1P_OFF  (WP_OFF + WP_SZ)
#define W1P_SZ   (8*8*64*16)       // 65536
#define W2P_OFF  (W1P_OFF + W1P_SZ)
#define W2P_SZ   (8*4*64*16)       // 32768
#define WZP_OFF  (W2P_OFF + W2P_SZ)
#define WZP_SZ   (4*4*64*16)       // 16384
#define WS_NEEDED ((size_t)(WZP_OFF + WZP_SZ))   // 770048 B

// s_waitcnt imm: wait until <=N vmem outstanding (expcnt/lgkmcnt don't care)
#define WAITVM(N) (((N) & 0xF) | (0x7 << 4) | (0xF << 8) | (((N) >> 4) << 14))

// raw barrier: LDS writes visible, VMEM (DMA) loads STAY IN FLIGHT
#define BAR() do {                                                  \
    asm volatile("s_waitcnt lgkmcnt(0)" ::: "memory");              \
    __builtin_amdgcn_sched_barrier(0);                              \
    __builtin_amdgcn_s_barrier();                                   \
    __builtin_amdgcn_sched_barrier(0);                              \
} while (0)

// ---- fast transcendentals ------------------------------------------------
#if __has_builtin(__builtin_amdgcn_exp2f)
#define EXP2F(x) __builtin_amdgcn_exp2f(x)
#else
#define EXP2F(x) exp2f(x)
#endif
#if __has_builtin(__builtin_amdgcn_logf)
#define LOG2F(x) __builtin_amdgcn_logf(x)
#else
#define LOG2F(x) log2f(x)
#endif
#if __has_builtin(__builtin_amdgcn_rcpf)
#define RCPF(x) __builtin_amdgcn_rcpf(x)
#else
#define RCPF(x) (1.0f/(x))
#endif

__device__ __forceinline__ float fsigmoid(float x) {
    return RCPF(1.0f + EXP2F(-1.4426950408889634f * x));
}
__device__ __forceinline__ float ftanh(float x) {
    return 1.0f - 2.0f * RCPF(1.0f + EXP2F(2.8853900817779268f * x));
}

// async 16B/lane global->LDS DMA; LDS base wave-uniform, lands at +lane*16
__device__ __forceinline__ void dma16(const void* g, void* lds) {
    __builtin_amdgcn_global_load_lds(
        (const __attribute__((address_space(1))) void*)g,
        (__attribute__((address_space(3))) void*)lds,
        16, 0, 0);
}

// ---------------- prep: f32 weights -> bf16 B-fragment-linear in ws -------
// Gate K remap (R6/R9-verified): k<256 -> h (Whh col k); 256<=k<288 -> z
// (Wih col 8+(k-256)); 288<=k<296 -> a (Wih col k-288); else 0.
__global__ void prep_kernel(const float* __restrict__ Wih, const float* __restrict__ Whh,
                            const float* __restrict__ W1,  const float* __restrict__ W2,
                            const float* __restrict__ Wz,  unsigned char* __restrict__ ws)
{
    int id = blockIdx.x * blockDim.x + threadIdx.x;
    __bf16* Wp  = (__bf16*)(ws + WP_OFF);
    __bf16* W1p = (__bf16*)(ws + W1P_OFF);
    __bf16* W2p = (__bf16*)(ws + W2P_OFF);
    __bf16* Wzp = (__bf16*)(ws + WZP_OFF);
    if (id < 40960) {                       // gates: 64 ct x 10 ki x 64 lanes
        int ct = id / 640, rem = id % 640;
        int ki = rem / 64, lane = rem % 64;
        int row = ct * 16 + (lane & 15);                 // gate-output col
        int kb  = ki * 32 + (lane >> 4) * 8;
        for (int j = 0; j < 8; ++j) {
            int k = kb + j;
            float v;
            if (k < 256)      v = Whh[row * 256 + k];            // h block
            else if (k < 288) v = Wih[row * 40 + 8 + (k - 256)]; // z block
            else if (k < 296) v = Wih[row * 40 + (k - 288)];     // a block
            else              v = 0.0f;                          // pad
            Wp[((size_t)(ki * 64 + ct) * 64 + lane) * 8 + j] = (__bf16)v;
        }
    } else if (id < 45056) {                // W1: 8 ct x 8 ki (ct-major)
        int id2 = id - 40960;
        int rem = id2 % 512, lane = rem % 64;
        int row = (id2 / 512) * 16 + (lane & 15);
        int kb  = (rem / 64) * 32 + (lane >> 4) * 8;
        for (int j = 0; j < 8; ++j) W1p[(size_t)id2 * 8 + j] = (__bf16)W1[row * 256 + kb + j];
    } else if (id < 47104) {                // W2: 8 ct x 4 ki
        int id3 = id - 45056;
        int rem = id3 % 256, lane = rem % 64;
        int row = (id3 / 256) * 16 + (lane & 15);
        int kb  = (rem / 64) * 32 + (lane >> 4) * 8;
        for (int j = 0; j < 8; ++j) W2p[(size_t)id3 * 8 + j] = (__bf16)W2[row * 128 + kb + j];
    } else if (id < 48128) {                // Wz: 4 ct x 4 ki
        int id4 = id - 47104;
        int rem = id4 % 256, lane = rem % 64;
        int row = (id4 / 256) * 16 + (lane & 15);
        int kb  = (rem / 64) * 32 + (lane >> 4) * 8;
        for (int j = 0; j < 8; ++j) Wzp[(size_t)id4 * 8 + j] = (__bf16)Wz[row * 128 + kb + j];
    }
}

// ---------------- fast path: 64 blocks x 512 threads (8 waves) ------------
// R10: single-role interleaved pipeline (R8 DMA ring + R6 K-reorder).
// Step t: xh[cb] holds h(t-1)|z(t-1,written P3)|a(t). 4 raw barriers:
//  P1: gates ki0..7 (stream, vmcnt-gated) interleaved with u1=MLP1(h(t-1))
//      (SAME af fragments feed both). u1s write. BAR1.
//  P2: gates ki9 (a) + u2 (W2 LDS-resident). u2s write. BAR2.
//  P3: zz loc/raw (waves 0-1) + softplus -> z(t-1) into xh[cb].z + out. BAR3.
//  P4: gates ki8 (z) + LSTM cell -> h(t) into xh[nb]; a(t+1) stage. BAR4.
// vmcnt counts: steady W(4); W(9) for ki1 (eps+a issued between ki0/ki1,
// wave-UNIFORM: all waves load clamped indices so counts match).
__global__ __launch_bounds__(512) void seq_mfma(
    const float* __restrict__ A,   const float* __restrict__ eps,
    const float* __restrict__ z0,  const float* __restrict__ h0,
    const float* __restrict__ c0,
    const float* __restrict__ bih, const float* __restrict__ bhh,
    const float* __restrict__ b1,  const float* __restrict__ b2,
    const float* __restrict__ bz,
    const unsigned char* __restrict__ ws, float* __restrict__ out)
{
    const int tid  = threadIdx.x;
    const int w    = tid >> 6;          // wave 0..7
    const int lane = tid & 63;
    const int lrow = lane & 15;
    const int quad = lane >> 4;
    const int n0   = blockIdx.x * 16;

    __shared__ __align__(16) __bf16 slots[8][2][2048];   // 64 KB DMA rings
    __shared__ __align__(16) __bf16 wmlp2[(W2P_SZ + WZP_SZ) / 2];  // 48 KB
    __shared__ __align__(16) __bf16 xh[2][16][328];      // [h|z|a|pad]
    __shared__ __align__(16) __bf16 u1s[16][136];
    __shared__ __align__(16) __bf16 u2s[16][136];

    const char* wsb = (const char*)ws;

    // one-time: W2|Wz global -> LDS (3072 x 16B)
    {
        const float4* src = (const float4*)(wsb + W2P_OFF);
        float4* dst = (float4*)wmlp2;
        for (int i = tid; i < 3072; i += 512) dst[i] = src[i];
    }
    const __bf16* w2l = wmlp2;            // ct*2048 + ki*512 + lane*8
    const __bf16* wzl = wmlp2 + 16384;    // ct*2048 + ki*512 + lane*8

    // init both xh buffers: h0 | z0 | a=0 | pad 0
    for (int idx = tid; idx < 2 * 16 * 320; idx += 512) {
        int b = idx / (16 * 320);
        int rem = idx % (16 * 320);
        int r = rem / 320, col = rem % 320;
        float v;
        if (col < 256)      v = h0[col];
        else if (col < 288) v = z0[col - 256];
        else                v = 0.0f;
        xh[b][r][col] = (__bf16)v;
    }
    if (tid < 128)   // a(t=0)
        xh[0][tid >> 3][288 + (tid & 7)] =
            (__bf16)A[((size_t)(n0 + (tid >> 3)) * T_LEN + 0) * 8 + (tid & 7)];

    // W1 VGPR-resident (ct = w): 32 regs
    bf16x8 w1f[8];
    #pragma unroll
    for (int k = 0; k < 8; ++k)
        w1f[k] = *(const bf16x8*)(wsb + W1P_OFF + ((size_t)(w * 8 + k) * 64 + lane) * 16);

    // biases & recurrent state (R8-proven mapping)
    float gb[4][2];
    #pragma unroll
    for (int g = 0; g < 4; ++g)
        #pragma unroll
        for (int j = 0; j < 2; ++j) {
            int unit = 32 * w + 16 * j + lrow;
            gb[g][j] = bih[g * 256 + unit] + bhh[g * 256 + unit];
        }
    float u1b = b1[w * 16 + lrow];
    float u2b = b2[w * 16 + lrow];
    float bzl = bz[(w & 1) * 16 + lrow];
    float bzr = bz[32 + (w & 1) * 16 + lrow];
    float cst[2][4];
    #pragma unroll
    for (int j = 0; j < 2; ++j) {
        float cv = c0[32 * w + 16 * j + lrow];
        #pragma unroll
        for (int r = 0; r < 4; ++r) cst[j][r] = cv;
    }

    #define WAITN(N) do { __builtin_amdgcn_s_waitcnt(WAITVM(N)); \
        __builtin_amdgcn_sched_barrier(0); } while (0)
    #define RFILL(RKI, H) do {                                                  \
        _Pragma("unroll")                                                       \
        for (int gg = 0; gg < 2; ++gg)                                          \
            _Pragma("unroll")                                                   \
            for (int j = 0; j < 2; ++j)                                         \
                dma16(wsb + WP_OFF + (size_t)(RKI) * 65536 +                    \
                      ((size_t)((2 * (H) + gg) * 16 + 2 * w + j) * 1024) +      \
                      (size_t)lane * 16,                                        \
                      (void*)&slots[w][H][(gg * 2 + j) * 512]);                 \
    } while (0)
    #define CHALF(H) do {                                                       \
        _Pragma("unroll")                                                       \
        for (int gg = 0; gg < 2; ++gg)                                          \
            _Pragma("unroll")                                                   \
            for (int j = 0; j < 2; ++j) {                                       \
                bf16x8 b_ = *(const bf16x8*)&slots[w][H][(gg * 2 + j) * 512     \
                                                         + lane * 8];           \
                acc[2 * (H) + gg][j] = __builtin_amdgcn_mfma_f32_16x16x32_bf16( \
                    af, b_, acc[2 * (H) + gg][j], 0, 0, 0);                     \
            }                                                                   \
        __builtin_amdgcn_sched_barrier(0);                                      \
    } while (0)
    #define GATEKI(KI, RKI, WA, WB) do {                                        \
        bf16x8 af = *(const bf16x8*)&xh[cb][lrow][(KI) * 32 + quad * 8];        \
        WAITN(WA); CHALF(0); RFILL(RKI, 0);                                     \
        WAITN(WB); CHALF(1); RFILL(RKI, 1);                                     \
    } while (0)
    #define GATEKI_U1(KI, RKI, WA, WB) do {                                     \
        bf16x8 af = *(const bf16x8*)&xh[cb][lrow][(KI) * 32 + quad * 8];        \
        WAITN(WA); CHALF(0); RFILL(RKI, 0);                                     \
        WAITN(WB); CHALF(1); RFILL(RKI, 1);                                     \
        a1 = __builtin_amdgcn_mfma_f32_16x16x32_bf16(af, w1f[KI], a1, 0, 0, 0); \
    } while (0)

    // prologue: ki0 both halves in flight; syncthreads drains them
    RFILL(0, 0);
    RFILL(0, 1);
    __syncthreads();

    float epsr[4];
    float av = 0.0f;
    const int aidx = (w & 1) * 64 + lane;

    for (int t = 0; t < T_LEN; ++t) {
        const int cb = t & 1;        // h(t-1) | z(t-1 at P3) | a(t)
        const int nb = cb ^ 1;       // receives h(t), a(t+1)

        // ---- P1: gates ki0..7 (stream) interleaved with u1 = MLP1(h(t-1))
        floatx4 acc[4][2];
        #pragma unroll
        for (int g = 0; g < 4; ++g)
            #pragma unroll
            for (int j = 0; j < 2; ++j)
                acc[g][j] = (floatx4){gb[g][j], gb[g][j], gb[g][j], gb[g][j]};
        floatx4 a1 = (floatx4){u1b, u1b, u1b, u1b};

        GATEKI_U1(0, 1, 4, 4);
        // eps(t-1)/a(t+1), wave-UNIFORM issue (clamped idx; values gated later)
        __builtin_amdgcn_sched_barrier(0);
        {
            const int te = (t > 0) ? (t - 1) : 0;
            #pragma unroll
            for (int r = 0; r < 4; ++r)
                epsr[r] = eps[((size_t)(n0 + quad * 4 + r) * T_LEN + te) * 32
                              + (w & 1) * 16 + lrow];
            const int ta = (t + 1 < T_LEN) ? (t + 1) : (T_LEN - 1);
            av = A[((size_t)(n0 + (aidx >> 3)) * T_LEN + ta) * 8 + (aidx & 7)];
        }
        __builtin_amdgcn_sched_barrier(0);
        GATEKI_U1(1, 2, 9, 9);
        GATEKI_U1(2, 3, 4, 4);
        GATEKI_U1(3, 4, 4, 4);
        GATEKI_U1(4, 5, 4, 4);
        GATEKI_U1(5, 6, 4, 4);
        GATEKI_U1(6, 7, 4, 4);
        GATEKI_U1(7, 9, 4, 4);
        #pragma unroll
        for (int r = 0; r < 4; ++r)
            u1s[quad * 4 + r][w * 16 + lrow] = (__bf16)fmaxf(a1[r], 0.0f);
        BAR();   // BAR1: u1s ready

        // ---- P2: gates ki9 (a) + u2 (W2 LDS-resident)
        GATEKI(9, 8, 4, 4);
        {
            floatx4 a2 = (floatx4){u2b, u2b, u2b, u2b};
            #pragma unroll
            for (int ki = 0; ki < 4; ++ki) {
                bf16x8 af = *(const bf16x8*)&u1s[lrow][ki * 32 + quad * 8];
                bf16x8 bb = *(const bf16x8*)&w2l[w * 2048 + ki * 512 + lane * 8];
                a2 = __builtin_amdgcn_mfma_f32_16x16x32_bf16(af, bb, a2, 0, 0, 0);
            }
            #pragma unroll
            for (int r = 0; r < 4; ++r)
                u2s[quad * 4 + r][w * 16 + lrow] = (__bf16)fmaxf(a2[r], 0.0f);
        }
        BAR();   // BAR2: u2s ready

        // ---- P3: zz loc/raw + softplus -> z(t-1) (waves 0-1), skip t=0
        if (w < 2 && t > 0) {
            floatx4 aL = (floatx4){bzl, bzl, bzl, bzl};
            floatx4 aR = (floatx4){bzr, bzr, bzr, bzr};
            #pragma unroll
            for (int ki = 0; ki < 4; ++ki) {
                bf16x8 af = *(const bf16x8*)&u2s[lrow][ki * 32 + quad * 8];
                bf16x8 bl = *(const bf16x8*)&wzl[(w)     * 2048 + ki * 512 + lane * 8];
                bf16x8 br = *(const bf16x8*)&wzl[(w + 2) * 2048 + ki * 512 + lane * 8];
                aL = __builtin_amdgcn_mfma_f32_16x16x32_bf16(af, bl, aL, 0, 0, 0);
                aR = __builtin_amdgcn_mfma_f32_16x16x32_bf16(af, br, aR, 0, 0, 0);
            }
            #pragma unroll
            for (int r = 0; r < 4; ++r) {
                float raw = aR[r];
                float sp  = (raw > 20.0f)
                          ? raw
                          : 0.6931471805599453f *
                            LOG2F(1.0f + EXP2F(1.4426950408889634f * raw));
                float zv  = aL[r] + sp * epsr[r];
                xh[cb][quad * 4 + r][256 + w * 16 + lrow] = (__bf16)zv;
                out[((size_t)(n0 + quad * 4 + r) * T_LEN + (t - 1)) * 32
                    + w * 16 + lrow] = zv;
            }
        }
        BAR();   // BAR3: z(t-1) staged in xh[cb]

        // ---- P4: gates ki8 (z) + LSTM cell -> h(t); a(t+1) stage
        GATEKI(8, 0, 4, 4);   // refills next-step ki0
        #pragma unroll
        for (int j = 0; j < 2; ++j)
            #pragma unroll
            for (int r = 0; r < 4; ++r) {
                float iv = fsigmoid(acc[0][j][r]);
                float fv = fsigmoid(acc[1][j][r]);
                float gv = ftanh(acc[2][j][r]);
                float ov = fsigmoid(acc[3][j][r]);
                float cn = fv * cst[j][r] + iv * gv;
                cst[j][r] = cn;
                xh[nb][quad * 4 + r][32 * w + 16 * j + lrow] = (__bf16)(ov * ftanh(cn));
            }
        if (w < 2 && t + 1 < T_LEN)
            xh[nb][aidx >> 3][288 + (aidx & 7)] = (__bf16)av;
        BAR();   // BAR4: h(t) + a(t+1) staged in xh[nb]
    }

    // ---- epilogue: z(127) = MLP(h(127)); h(127) is in xh[0]
    asm volatile("s_waitcnt vmcnt(0)" ::: "memory");
    __builtin_amdgcn_sched_barrier(0);
    {
        #pragma unroll
        for (int r = 0; r < 4; ++r)
            epsr[r] = eps[((size_t)(n0 + quad * 4 + r) * T_LEN + (T_LEN - 1)) * 32
                          + (w & 1) * 16 + lrow];
        floatx4 a1 = (floatx4){u1b, u1b, u1b, u1b};
        #pragma unroll
        for (int ki = 0; ki < 8; ++ki) {
            bf16x8 af = *(const bf16x8*)&xh[0][lrow][ki * 32 + quad * 8];
            a1 = __builtin_amdgcn_mfma_f32_16x16x32_bf16(af, w1f[ki], a1, 0, 0, 0);
        }
        #pragma unroll
        for (int r = 0; r < 4; ++r)
            u1s[quad * 4 + r][w * 16 + lrow] = (__bf16)fmaxf(a1[r], 0.0f);
        BAR();
        floatx4 a2 = (floatx4){u2b, u2b, u2b, u2b};
        #pragma unroll
        for (int ki = 0; ki < 4; ++ki) {
            bf16x8 af = *(const bf16x8*)&u1s[lrow][ki * 32 + quad * 8];
            bf16x8 bb = *(const bf16x8*)&w2l[w * 2048 + ki * 512 + lane * 8];
            a2 = __builtin_amdgcn_mfma_f32_16x16x32_bf16(af, bb, a2, 0, 0, 0);
        }
        #pragma unroll
        for (int r = 0; r < 4; ++r)
            u2s[quad * 4 + r][w * 16 + lrow] = (__bf16)fmaxf(a2[r], 0.0f);
        BAR();
        if (w < 2) {
            floatx4 aL = (floatx4){bzl, bzl, bzl, bzl};
            floatx4 aR = (floatx4){bzr, bzr, bzr, bzr};
            #pragma unroll
            for (int ki = 0; ki < 4; ++ki) {
                bf16x8 af = *(const bf16x8*)&u2s[lrow][ki * 32 + quad * 8];
                bf16x8 bl = *(const bf16x8*)&wzl[(w)     * 2048 + ki * 512 + lane * 8];
                bf16x8 br = *(const bf16x8*)&wzl[(w + 2) * 2048 + ki * 512 + lane * 8];
                aL = __builtin_amdgcn_mfma_f32_16x16x32_bf16(af, bl, aL, 0, 0, 0);
                aR = __builtin_amdgcn_mfma_f32_16x16x32_bf16(af, br, aR, 0, 0, 0);
            }
            #pragma unroll
            for (int r = 0; r < 4; ++r) {
                float raw = aR[r];
                float sp  = (raw > 20.0f)
                          ? raw
                          : 0.6931471805599453f *
                            LOG2F(1.0f + EXP2F(1.4426950408889634f * raw));
                float zv  = aL[r] + sp * epsr[r];
                out[((size_t)(n0 + quad * 4 + r) * T_LEN + (T_LEN - 1)) * 32
                    + w * 16 + lrow] = zv;
            }
        }
    }
    #undef GATEKI_U1
    #undef GATEKI
    #undef CHALF
    #undef RFILL
    #undef WAITN
}

// ---------------- fallback: proven R4 VALU kernel (f32 hard-coded) --------
struct SM {
    float zx[4][40]; float h[4][256]; float u1[4][128]; float u2[4][128]; float zz[4][64];
};

__global__ __launch_bounds__(256) void seq_valu(
    const float* __restrict__ A, const float* __restrict__ eps,
    const float* __restrict__ z0, const float* __restrict__ h0, const float* __restrict__ c0,
    const float* __restrict__ Wih, const float* __restrict__ Whh,
    const float* __restrict__ bih, const float* __restrict__ bhh,
    const float* __restrict__ W1, const float* __restrict__ b1,
    const float* __restrict__ W2, const float* __restrict__ b2,
    const float* __restrict__ Wz, const float* __restrict__ bz, float* __restrict__ out)
{
    __shared__ SM sm;
    const int tid = threadIdx.x;
    const int n0  = blockIdx.x * 4;
    if (tid < 128) { int rr = tid >> 5, cc = tid & 31; sm.zx[rr][8 + cc] = z0[cc]; }
    for (int i = tid; i < 4 * 256; i += 256) sm.h[i >> 8][i & 255] = h0[i & 255];
    float c[4];
    #pragma unroll
    for (int rr = 0; rr < 4; ++rr) c[rr] = c0[tid];
    float gbias[4];
    #pragma unroll
    for (int g = 0; g < 4; ++g) gbias[g] = bih[g * 256 + tid] + bhh[g * 256 + tid];

    for (int t = 0; t < T_LEN; ++t) {
        if (tid < 32) { int rr = tid >> 3, cc = tid & 7;
            sm.zx[rr][cc] = A[((size_t)(n0 + rr) * T_LEN + t) * 8 + cc]; }
        __syncthreads();
        float acc[4][4];
        #pragma unroll
        for (int g = 0; g < 4; ++g)
            #pragma unroll
            for (int rr = 0; rr < 4; ++rr) acc[g][rr] = gbias[g];
        for (int k = 0; k < 40; ++k) {
            float xv[4];
            #pragma unroll
            for (int rr = 0; rr < 4; ++rr) xv[rr] = sm.zx[rr][k];
            #pragma unroll
            for (int g = 0; g < 4; ++g) {
                float w = Wih[(size_t)(g * 256 + tid) * 40 + k];
                #pragma unroll
                for (int rr = 0; rr < 4; ++rr) acc[g][rr] += w * xv[rr];
            }
        }
        for (int k = 0; k < 256; ++k) {
            float hv[4];
            #pragma unroll
            for (int rr = 0; rr < 4; ++rr) hv[rr] = sm.h[rr][k];
            #pragma unroll
            for (int g = 0; g < 4; ++g) {
                float w = Whh[(size_t)(g * 256 + tid) * 256 + k];
                #pragma unroll
                for (int rr = 0; rr < 4; ++rr) acc[g][rr] += w * hv[rr];
            }
        }
        __syncthreads();
        #pragma unroll
        for (int rr = 0; rr < 4; ++rr) {
            float iv = 1.0f / (1.0f + expf(-acc[0][rr]));
            float fv = 1.0f / (1.0f + expf(-acc[1][rr]));
            float gv = tanhf(acc[2][rr]);
            float ov = 1.0f / (1.0f + expf(-acc[3][rr]));
            float cn = fv * c[rr] + iv * gv;
            c[rr] = cn;
            sm.h[rr][tid] = ov * tanhf(cn);
        }
        __syncthreads();
        { int col = tid & 127, rb = (tid >> 7) * 2;
          float a0 = b1[col], a1 = a0;
          for (int k = 0; k < 256; ++k) { float w = W1[(size_t)col * 256 + k];
              a0 += w * sm.h[rb][k]; a1 += w * sm.h[rb + 1][k]; }
          sm.u1[rb][col] = fmaxf(a0, 0.0f); sm.u1[rb + 1][col] = fmaxf(a1, 0.0f); }
        __syncthreads();
        { int col = tid & 127, rb = (tid >> 7) * 2;
          float a0 = b2[col], a1 = a0;
          for (int k = 0; k < 128; ++k) { float w = W2[(size_t)col * 128 + k];
              a0 += w * sm.u1[rb][k]; a1 += w * sm.u1[rb + 1][k]; }
          sm.u2[rb][col] = fmaxf(a0, 0.0f); sm.u2[rb + 1][col] = fmaxf(a1, 0.0f); }
        __syncthreads();
        { int rr = tid >> 6, col = tid & 63;
          float a0 = bz[col];
          for (int k = 0; k < 128; ++k) a0 += Wz[(size_t)col * 128 + k] * sm.u2[rr][k];
          sm.zz[rr][col] = a0; }
        __syncthreads();
        if (tid < 128) {
            int rr = tid >> 5, cc = tid & 31;
            float loc = sm.zz[rr][cc], raw = sm.zz[rr][cc + 32];
            float sp  = (raw > 20.0f) ? raw : log1pf(expf(raw));
            float ev  = eps[((size_t)(n0 + rr) * T_LEN + t) * 32 + cc];
            float zv  = loc + sp * ev;
            sm.zx[rr][8 + cc] = zv;
            out[((size_t)(n0 + rr) * T_LEN + t) * 32 + cc] = zv;
        }
        __syncthreads();
    }
}

extern "C" void kernel_launch(void* const* d_in, const int* in_sizes, int n_in,
                              void* d_out, int out_size, void* d_ws, size_t ws_size,
                              hipStream_t stream)
{
    const float* A   = (const float*)d_in[0];
    const float* eps = (const float*)d_in[1];
    const float* z0  = (const float*)d_in[2];
    const float* h0  = (const float*)d_in[3];
    const float* c0  = (const float*)d_in[4];
    const float* Wih = (const float*)d_in[5];
    const float* Whh = (const float*)d_in[6];
    const float* bih = (const float*)d_in[7];
    const float* bhh = (const float*)d_in[8];
    const float* W1  = (const float*)d_in[9];
    const float* b1  = (const float*)d_in[10];
    const float* W2  = (const float*)d_in[11];
    const float* b2  = (const float*)d_in[12];
    const float* Wz  = (const float*)d_in[13];
    const float* bz  = (const float*)d_in[14];
    float* out = (float*)d_out;

    if (ws_size >= WS_NEEDED) {
        prep_kernel<<<188, 256, 0, stream>>>(Wih, Whh, W1, W2, Wz, (unsigned char*)d_ws);
        seq_mfma<<<64, 512, 0, stream>>>(A, eps, z0, h0, c0,
                                         bih, bhh, b1, b2, bz,
                                         (const unsigned char*)d_ws, out);
    } else {
        seq_valu<<<256, 256, 0, stream>>>(A, eps, z0, h0, c0, Wih, Whh, bih, bhh,
                                          W1, b1, W2, b2, Wz, bz, out);
    }
}

// Round 11
// 1588.510 us; speedup vs baseline: 1.1785x; 1.0064x over previous
//
#include <hip/hip_runtime.h>
#include <hip/hip_bf16.h>
#include <math.h>

typedef __bf16 bf16x8 __attribute__((ext_vector_type(8)));
typedef float floatx4 __attribute__((ext_vector_type(4)));

#define T_LEN 128

// ws layout: bf16 fragment-packed weights, gates KI-MAJOR:
//   gate frag addr = WP_OFF + ki*65536 + ct*1024 + lane*16
// K order: [ a(8) | z(32) | h(256) | pad(24) ]   (R8's verified layout)
#define WP_OFF   0
#define WP_SZ    (64*10*64*16)     // 655360
#define W1P_OFF  (WP_OFF + WP_SZ)
#define W1P_SZ   (8*8*64*16)       // 65536
#define W2P_OFF  (W1P_OFF + W1P_SZ)
#define W2P_SZ   (8*4*64*16)       // 32768
#define WZP_OFF  (W2P_OFF + W2P_SZ)
#define WZP_SZ   (4*4*64*16)       // 16384
#define WS_NEEDED ((size_t)(WZP_OFF + WZP_SZ))   // 770048 B

// s_waitcnt imm: wait until <=N vmem outstanding (expcnt/lgkmcnt don't care)
#define WAITVM(N) (((N) & 0xF) | (0x7 << 4) | (0xF << 8) | (((N) >> 4) << 14))

// raw barrier: LDS writes visible, VMEM (DMA) loads STAY IN FLIGHT
#define BAR() do {                                                  \
    asm volatile("s_waitcnt lgkmcnt(0)" ::: "memory");              \
    __builtin_amdgcn_sched_barrier(0);                              \
    __builtin_amdgcn_s_barrier();                                   \
    __builtin_amdgcn_sched_barrier(0);                              \
} while (0)

// ---- fast transcendentals ------------------------------------------------
#if __has_builtin(__builtin_amdgcn_exp2f)
#define EXP2F(x) __builtin_amdgcn_exp2f(x)
#else
#define EXP2F(x) exp2f(x)
#endif
#if __has_builtin(__builtin_amdgcn_logf)
#define LOG2F(x) __builtin_amdgcn_logf(x)
#else
#define LOG2F(x) log2f(x)
#endif
#if __has_builtin(__builtin_amdgcn_rcpf)
#define RCPF(x) __builtin_amdgcn_rcpf(x)
#else
#define RCPF(x) (1.0f/(x))
#endif

__device__ __forceinline__ float fsigmoid(float x) {
    return RCPF(1.0f + EXP2F(-1.4426950408889634f * x));
}
__device__ __forceinline__ float ftanh(float x) {
    return 1.0f - 2.0f * RCPF(1.0f + EXP2F(2.8853900817779268f * x));
}

// async 16B/lane global->LDS DMA; LDS base wave-uniform, lands at +lane*16
__device__ __forceinline__ void dma16(const void* g, void* lds) {
    __builtin_amdgcn_global_load_lds(
        (const __attribute__((address_space(1))) void*)g,
        (__attribute__((address_space(3))) void*)lds,
        16, 0, 0);
}

// ---------------- prep: f32 weights -> bf16 B-fragment-linear in ws -------
__global__ void prep_kernel(const float* __restrict__ Wih, const float* __restrict__ Whh,
                            const float* __restrict__ W1,  const float* __restrict__ W2,
                            const float* __restrict__ Wz,  unsigned char* __restrict__ ws)
{
    int id = blockIdx.x * blockDim.x + threadIdx.x;
    __bf16* Wp  = (__bf16*)(ws + WP_OFF);
    __bf16* W1p = (__bf16*)(ws + W1P_OFF);
    __bf16* W2p = (__bf16*)(ws + W2P_OFF);
    __bf16* Wzp = (__bf16*)(ws + WZP_OFF);
    if (id < 40960) {                       // gates: 64 ct x 10 ki x 64 lanes
        int ct = id / 640, rem = id % 640;
        int ki = rem / 64, lane = rem % 64;
        int row = ct * 16 + (lane & 15);                 // gate-output col
        int kb  = ki * 32 + (lane >> 4) * 8;
        for (int j = 0; j < 8; ++j) {
            int k = kb + j;
            float v;
            if (k < 40)       v = Wih[row * 40 + k];     // [a|z] = Wih cols
            else if (k < 296) v = Whh[row * 256 + (k - 40)];
            else              v = 0.0f;                   // pad 296..319
            Wp[((size_t)(ki * 64 + ct) * 64 + lane) * 8 + j] = (__bf16)v;
        }
    } else if (id < 45056) {                // W1: 8 ct x 8 ki (ct-major)
        int id2 = id - 40960;
        int rem = id2 % 512, lane = rem % 64;
        int row = (id2 / 512) * 16 + (lane & 15);
        int kb  = (rem / 64) * 32 + (lane >> 4) * 8;
        for (int j = 0; j < 8; ++j) W1p[(size_t)id2 * 8 + j] = (__bf16)W1[row * 256 + kb + j];
    } else if (id < 47104) {                // W2: 8 ct x 4 ki
        int id3 = id - 45056;
        int rem = id3 % 256, lane = rem % 64;
        int row = (id3 / 256) * 16 + (lane & 15);
        int kb  = (rem / 64) * 32 + (lane >> 4) * 8;
        for (int j = 0; j < 8; ++j) W2p[(size_t)id3 * 8 + j] = (__bf16)W2[row * 128 + kb + j];
    } else if (id < 48128) {                // Wz: 4 ct x 4 ki
        int id4 = id - 47104;
        int rem = id4 % 256, lane = rem % 64;
        int row = (id4 / 256) * 16 + (lane & 15);
        int kb  = (rem / 64) * 32 + (lane >> 4) * 8;
        for (int j = 0; j < 8; ++j) Wzp[(size_t)id4 * 8 + j] = (__bf16)Wz[row * 128 + kb + j];
    }
}

// ---------------- fast path: 64 blocks x 512 threads (8 waves) ------------
// R11 = R8 skeleton + DEPTH-4 DMA ring (16 KB in flight per wave) + W2/Wz
// routed through the ring (frees 48 KB LDS to pay for the deeper ring).
// Per-step unit stream (per wave): g0..g19 (gate ki0H0..ki9H1), m0 (W2),
// m1 (Wz). 22 units/step, slot = global_unit % 4 -> slot offset rotates by
// 2 each step -> two-step-unrolled loop with compile-time OFF in {0,2}.
// Refill rule: consuming unit u issues unit u+4 into the SAME slot.
// Waits (derived by queue sim, uniform issue incl. eps/A by all waves):
//   units 0..3: vmcnt(14); units 4..21: vmcnt(12). Never drained.
__global__ __launch_bounds__(512) void seq_mfma(
    const float* __restrict__ A,   const float* __restrict__ eps,
    const float* __restrict__ z0,  const float* __restrict__ h0,
    const float* __restrict__ c0,
    const float* __restrict__ bih, const float* __restrict__ bhh,
    const float* __restrict__ b1,  const float* __restrict__ b2,
    const float* __restrict__ bz,
    const unsigned char* __restrict__ ws, float* __restrict__ out)
{
    const int tid  = threadIdx.x;
    const int w    = tid >> 6;          // wave 0..7
    const int lane = tid & 63;
    const int lrow = lane & 15;
    const int quad = lane >> 4;
    const int n0   = blockIdx.x * 16;

    __shared__ __align__(16) __bf16 slots[8][4][2048];   // 128 KB DMA rings
    __shared__ __align__(16) __bf16 xh[2][16][328];      // [a|z|h|pad] 20.5 KB
    __shared__ __align__(16) __bf16 u1s[16][136];        // + zz f32 overlay
    __shared__ __align__(16) __bf16 u2s[16][136];
    float* zzf = (float*)&u1s[0][0];                     // [16][68] f32 view

    const char* wsb = (const char*)ws;

    // init both xh buffers: a(0)=0 | z0 | h0 | pad 0
    for (int idx = tid; idx < 2 * 16 * 320; idx += 512) {
        int b = idx / (16 * 320);
        int rem = idx % (16 * 320);
        int r = rem / 320, col = rem % 320;
        float v;
        if (col >= 8 && col < 40)        v = z0[col - 8];
        else if (col >= 40 && col < 296) v = h0[col - 40];
        else                             v = 0.0f;
        xh[b][r][col] = (__bf16)v;
    }
    if (tid < 128)   // a(t=0)
        xh[0][tid >> 3][tid & 7] =
            (__bf16)A[((size_t)(n0 + (tid >> 3)) * T_LEN + 0) * 8 + (tid & 7)];

    // W1 VGPR-resident (ct = w): 32 regs
    bf16x8 w1f[8];
    #pragma unroll
    for (int k = 0; k < 8; ++k)
        w1f[k] = *(const bf16x8*)(wsb + W1P_OFF + ((size_t)(w * 8 + k) * 64 + lane) * 16);

    // biases & recurrent state (R8-proven mapping)
    float gb[4][2];
    #pragma unroll
    for (int g = 0; g < 4; ++g)
        #pragma unroll
        for (int j = 0; j < 2; ++j) {
            int unit = 32 * w + 16 * j + lrow;
            gb[g][j] = bih[g * 256 + unit] + bhh[g * 256 + unit];
        }
    float u1b = b1[w * 16 + lrow];
    float u2b = b2[w * 16 + lrow];
    float zzb = (w < 4) ? bz[w * 16 + lrow] : 0.0f;
    float cst[2][4];
    #pragma unroll
    for (int j = 0; j < 2; ++j) {
        float cv = c0[32 * w + 16 * j + lrow];
        #pragma unroll
        for (int r = 0; r < 4; ++r) cst[j][r] = cv;
    }

    // ---- ring macros (all compile-time slot/ki indices) ----
    #define DMAG(KI, H, SL) do {                                                \
        _Pragma("unroll")                                                       \
        for (int gg = 0; gg < 2; ++gg)                                          \
            _Pragma("unroll")                                                   \
            for (int j = 0; j < 2; ++j)                                         \
                dma16(wsb + WP_OFF + (size_t)(KI) * 65536 +                     \
                      ((size_t)((2 * (H) + gg) * 16 + 2 * w + j) * 1024) +      \
                      (size_t)lane * 16,                                        \
                      (void*)&slots[w][SL][(gg * 2 + j) * 512]);                \
    } while (0)
    #define DMAW2(SL) do {                                                      \
        _Pragma("unroll")                                                       \
        for (int i = 0; i < 4; ++i)                                             \
            dma16(wsb + W2P_OFF + (size_t)w * 4096 + i * 1024 +                 \
                  (size_t)lane * 16, (void*)&slots[w][SL][i * 512]);            \
    } while (0)
    #define DMAWZ(SL) do {                                                      \
        _Pragma("unroll")                                                       \
        for (int i = 0; i < 4; ++i)                                             \
            dma16(wsb + WZP_OFF + (size_t)(w & 3) * 4096 + i * 1024 +           \
                  (size_t)lane * 16, (void*)&slots[w][SL][i * 512]);            \
    } while (0)
    #define CONSG(H, SL, WN) do {                                               \
        __builtin_amdgcn_s_waitcnt(WAITVM(WN));                                 \
        __builtin_amdgcn_sched_barrier(0);                                      \
        _Pragma("unroll")                                                       \
        for (int gg = 0; gg < 2; ++gg)                                          \
            _Pragma("unroll")                                                   \
            for (int j = 0; j < 2; ++j) {                                       \
                bf16x8 b_ = *(const bf16x8*)&slots[w][SL][(gg * 2 + j) * 512    \
                                                          + lane * 8];          \
                acc[2 * (H) + gg][j] = __builtin_amdgcn_mfma_f32_16x16x32_bf16( \
                    af, b_, acc[2 * (H) + gg][j], 0, 0, 0);                     \
            }                                                                   \
        __builtin_amdgcn_sched_barrier(0);                                      \
    } while (0)

    const int aidx = (w & 1) * 64 + lane;
    float eps_cur, eps_nxt, av;

    // prologue: units 0..3 (ki0,ki1) + eps(0) + A[1]; syncthreads drains all
    DMAG(0, 0, 0);
    DMAG(0, 1, 1);
    DMAG(1, 0, 2);
    DMAG(1, 1, 3);
    eps_cur = eps[((size_t)(n0 + (tid >> 5)) * T_LEN + 0) * 32 + (tid & 31)];
    av      = A[((size_t)(n0 + (aidx >> 3)) * T_LEN + 1) * 8 + (aidx & 7)];
    __syncthreads();

    #define STEPBODY(OFF, T) do {                                               \
        const int cb = (T) & 1;                                                 \
        const int nb = cb ^ 1;                                                  \
        floatx4 acc[4][2];                                                      \
        _Pragma("unroll")                                                       \
        for (int g = 0; g < 4; ++g)                                             \
            _Pragma("unroll")                                                   \
            for (int j = 0; j < 2; ++j)                                         \
                acc[g][j] = (floatx4){gb[g][j], gb[g][j], gb[g][j], gb[g][j]};  \
        {   /* gates: units 0..19, refill distance 4 units (2 ki) */            \
            bf16x8 af;                                                          \
            af = *(const bf16x8*)&xh[cb][lrow][0 * 32 + quad * 8];              \
            CONSG(0, (0  + (OFF)) & 3, 14);  DMAG(2, 0, (0  + (OFF)) & 3);      \
            CONSG(1, (1  + (OFF)) & 3, 14);  DMAG(2, 1, (1  + (OFF)) & 3);      \
            af = *(const bf16x8*)&xh[cb][lrow][1 * 32 + quad * 8];              \
            CONSG(0, (2  + (OFF)) & 3, 14);  DMAG(3, 0, (2  + (OFF)) & 3);      \
            CONSG(1, (3  + (OFF)) & 3, 14);  DMAG(3, 1, (3  + (OFF)) & 3);      \
            af = *(const bf16x8*)&xh[cb][lrow][2 * 32 + quad * 8];              \
            CONSG(0, (4  + (OFF)) & 3, 12);  DMAG(4, 0, (4  + (OFF)) & 3);      \
            CONSG(1, (5  + (OFF)) & 3, 12);  DMAG(4, 1, (5  + (OFF)) & 3);      \
            af = *(const bf16x8*)&xh[cb][lrow][3 * 32 + quad * 8];              \
            CONSG(0, (6  + (OFF)) & 3, 12);  DMAG(5, 0, (6  + (OFF)) & 3);      \
            CONSG(1, (7  + (OFF)) & 3, 12);  DMAG(5, 1, (7  + (OFF)) & 3);      \
            af = *(const bf16x8*)&xh[cb][lrow][4 * 32 + quad * 8];              \
            CONSG(0, (8  + (OFF)) & 3, 12);  DMAG(6, 0, (8  + (OFF)) & 3);      \
            CONSG(1, (9  + (OFF)) & 3, 12);  DMAG(6, 1, (9  + (OFF)) & 3);      \
            af = *(const bf16x8*)&xh[cb][lrow][5 * 32 + quad * 8];              \
            CONSG(0, (10 + (OFF)) & 3, 12);  DMAG(7, 0, (10 + (OFF)) & 3);      \
            CONSG(1, (11 + (OFF)) & 3, 12);  DMAG(7, 1, (11 + (OFF)) & 3);      \
            af = *(const bf16x8*)&xh[cb][lrow][6 * 32 + quad * 8];              \
            CONSG(0, (12 + (OFF)) & 3, 12);  DMAG(8, 0, (12 + (OFF)) & 3);      \
            CONSG(1, (13 + (OFF)) & 3, 12);  DMAG(8, 1, (13 + (OFF)) & 3);      \
            af = *(const bf16x8*)&xh[cb][lrow][7 * 32 + quad * 8];              \
            CONSG(0, (14 + (OFF)) & 3, 12);  DMAG(9, 0, (14 + (OFF)) & 3);      \
            CONSG(1, (15 + (OFF)) & 3, 12);  DMAG(9, 1, (15 + (OFF)) & 3);      \
            af = *(const bf16x8*)&xh[cb][lrow][8 * 32 + quad * 8];              \
            CONSG(0, (16 + (OFF)) & 3, 12);  DMAW2((16 + (OFF)) & 3);           \
            CONSG(1, (17 + (OFF)) & 3, 12);  DMAWZ((17 + (OFF)) & 3);           \
            af = *(const bf16x8*)&xh[cb][lrow][9 * 32 + quad * 8];              \
            CONSG(0, (18 + (OFF)) & 3, 12);  DMAG(0, 0, (18 + (OFF)) & 3);      \
            CONSG(1, (19 + (OFF)) & 3, 12);  DMAG(0, 1, (19 + (OFF)) & 3);      \
        }                                                                       \
        /* LSTM cell -> h(T) into xh[nb]; stage a(T+1) from av */               \
        _Pragma("unroll")                                                       \
        for (int j = 0; j < 2; ++j)                                             \
            _Pragma("unroll")                                                   \
            for (int r = 0; r < 4; ++r) {                                       \
                float iv = fsigmoid(acc[0][j][r]);                              \
                float fv = fsigmoid(acc[1][j][r]);                              \
                float gv = ftanh(acc[2][j][r]);                                 \
                float ov = fsigmoid(acc[3][j][r]);                              \
                float cn = fv * cst[j][r] + iv * gv;                            \
                cst[j][r] = cn;                                                 \
                xh[nb][quad * 4 + r][40 + 32 * w + 16 * j + lrow] =             \
                    (__bf16)(ov * ftanh(cn));                                   \
            }                                                                   \
        if (w < 2 && (T) + 1 < T_LEN)                                           \
            xh[nb][aidx >> 3][aidx & 7] = (__bf16)av;                           \
        BAR();   /* B2: h(T) + a(T+1) staged */                                 \
        {   /* u1 = relu(h @ W1^T + b1): W1 VGPR-resident */                    \
            floatx4 a1 = (floatx4){u1b, u1b, u1b, u1b};                         \
            _Pragma("unroll")                                                   \
            for (int ki = 0; ki < 8; ++ki) {                                    \
                bf16x8 af1 = *(const bf16x8*)&xh[nb][lrow][40 + ki * 32         \
                                                           + quad * 8];        \
                a1 = __builtin_amdgcn_mfma_f32_16x16x32_bf16(af1, w1f[ki],      \
                                                             a1, 0, 0, 0);      \
            }                                                                   \
            _Pragma("unroll")                                                   \
            for (int r = 0; r < 4; ++r)                                         \
                u1s[quad * 4 + r][w * 16 + lrow] = (__bf16)fmaxf(a1[r], 0.0f);  \
        }                                                                       \
        BAR();   /* B3: u1s ready */                                            \
        {   /* u2: consume m0 (W2) from ring; refill next ki1H0 */              \
            __builtin_amdgcn_s_waitcnt(WAITVM(12));                             \
            __builtin_amdgcn_sched_barrier(0);                                  \
            floatx4 a2 = (floatx4){u2b, u2b, u2b, u2b};                         \
            _Pragma("unroll")                                                   \
            for (int ki = 0; ki < 4; ++ki) {                                    \
                bf16x8 af2 = *(const bf16x8*)&u1s[lrow][ki * 32 + quad * 8];    \
                bf16x8 bb  = *(const bf16x8*)&slots[w][(20 + (OFF)) & 3]        \
                                                      [ki * 512 + lane * 8];    \
                a2 = __builtin_amdgcn_mfma_f32_16x16x32_bf16(af2, bb,           \
                                                             a2, 0, 0, 0);      \
            }                                                                   \
            _Pragma("unroll")                                                   \
            for (int r = 0; r < 4; ++r)                                         \
                u2s[quad * 4 + r][w * 16 + lrow] = (__bf16)fmaxf(a2[r], 0.0f);  \
            __builtin_amdgcn_sched_barrier(0);                                  \
            DMAG(1, 0, (20 + (OFF)) & 3);                                       \
        }                                                                       \
        BAR();   /* B4: u2s ready (u1s free for zz overlay) */                  \
        {   /* zz: consume m1 (Wz); waves 0-3 compute; refill next ki1H1 */     \
            __builtin_amdgcn_s_waitcnt(WAITVM(12));                             \
            __builtin_amdgcn_sched_barrier(0);                                  \
            if (w < 4) {                                                        \
                floatx4 a3 = (floatx4){zzb, zzb, zzb, zzb};                     \
                _Pragma("unroll")                                               \
                for (int ki = 0; ki < 4; ++ki) {                                \
                    bf16x8 af3 = *(const bf16x8*)&u2s[lrow][ki * 32             \
                                                            + quad * 8];       \
                    bf16x8 bb  = *(const bf16x8*)&slots[w][(21 + (OFF)) & 3]    \
                                                          [ki * 512 + lane * 8];\
                    a3 = __builtin_amdgcn_mfma_f32_16x16x32_bf16(af3, bb,       \
                                                                 a3, 0, 0, 0);  \
                }                                                               \
                _Pragma("unroll")                                               \
                for (int r = 0; r < 4; ++r)                                     \
                    zzf[(quad * 4 + r) * 68 + w * 16 + lrow] = a3[r];           \
            }                                                                   \
            __builtin_amdgcn_sched_barrier(0);                                  \
            DMAG(1, 1, (21 + (OFF)) & 3);                                       \
            const int te = ((T) + 1 < T_LEN) ? (T) + 1 : T_LEN - 1;             \
            eps_nxt = eps[((size_t)(n0 + (tid >> 5)) * T_LEN + te) * 32         \
                          + (tid & 31)];                                        \
            const int ta = ((T) + 2 < T_LEN) ? (T) + 2 : T_LEN - 1;             \
            av = A[((size_t)(n0 + (aidx >> 3)) * T_LEN + ta) * 8 + (aidx & 7)]; \
        }                                                                       \
        BAR();   /* B5: zz ready */                                             \
        {   /* z = loc + softplus(raw)*eps -> xh[nb].z + out */                 \
            int r = tid >> 5, c = tid & 31;                                     \
            float loc = zzf[r * 68 + c];                                        \
            float raw = zzf[r * 68 + c + 32];                                   \
            float sp  = (raw > 20.0f)                                           \
                      ? raw                                                     \
                      : 0.6931471805599453f *                                   \
                        LOG2F(1.0f + EXP2F(1.4426950408889634f * raw));         \
            float zv  = loc + sp * eps_cur;                                     \
            xh[nb][r][8 + c] = (__bf16)zv;                                      \
            out[((size_t)(n0 + r) * T_LEN + (T)) * 32 + c] = zv;                \
        }                                                                       \
        eps_cur = eps_nxt;                                                      \
        BAR();   /* B1: xh[nb] complete for next step */                        \
    } while (0)

    for (int t2 = 0; t2 < T_LEN; t2 += 2) {
        STEPBODY(0, t2);
        STEPBODY(2, t2 + 1);
    }
    #undef STEPBODY
    #undef CONSG
    #undef DMAWZ
    #undef DMAW2
    #undef DMAG
}

// ---------------- fallback: proven R4 VALU kernel (f32 hard-coded) --------
struct SM {
    float zx[4][40]; float h[4][256]; float u1[4][128]; float u2[4][128]; float zz[4][64];
};

__global__ __launch_bounds__(256) void seq_valu(
    const float* __restrict__ A, const float* __restrict__ eps,
    const float* __restrict__ z0, const float* __restrict__ h0, const float* __restrict__ c0,
    const float* __restrict__ Wih, const float* __restrict__ Whh,
    const float* __restrict__ bih, const float* __restrict__ bhh,
    const float* __restrict__ W1, const float* __restrict__ b1,
    const float* __restrict__ W2, const float* __restrict__ b2,
    const float* __restrict__ Wz, const float* __restrict__ bz, float* __restrict__ out)
{
    __shared__ SM sm;
    const int tid = threadIdx.x;
    const int n0  = blockIdx.x * 4;
    if (tid < 128) { int rr = tid >> 5, cc = tid & 31; sm.zx[rr][8 + cc] = z0[cc]; }
    for (int i = tid; i < 4 * 256; i += 256) sm.h[i >> 8][i & 255] = h0[i & 255];
    float c[4];
    #pragma unroll
    for (int rr = 0; rr < 4; ++rr) c[rr] = c0[tid];
    float gbias[4];
    #pragma unroll
    for (int g = 0; g < 4; ++g) gbias[g] = bih[g * 256 + tid] + bhh[g * 256 + tid];

    for (int t = 0; t < T_LEN; ++t) {
        if (tid < 32) { int rr = tid >> 3, cc = tid & 7;
            sm.zx[rr][cc] = A[((size_t)(n0 + rr) * T_LEN + t) * 8 + cc]; }
        __syncthreads();
        float acc[4][4];
        #pragma unroll
        for (int g = 0; g < 4; ++g)
            #pragma unroll
            for (int rr = 0; rr < 4; ++rr) acc[g][rr] = gbias[g];
        for (int k = 0; k < 40; ++k) {
            float xv[4];
            #pragma unroll
            for (int rr = 0; rr < 4; ++rr) xv[rr] = sm.zx[rr][k];
            #pragma unroll
            for (int g = 0; g < 4; ++g) {
                float w = Wih[(size_t)(g * 256 + tid) * 40 + k];
                #pragma unroll
                for (int rr = 0; rr < 4; ++rr) acc[g][rr] += w * xv[rr];
            }
        }
        for (int k = 0; k < 256; ++k) {
            float hv[4];
            #pragma unroll
            for (int rr = 0; rr < 4; ++rr) hv[rr] = sm.h[rr][k];
            #pragma unroll
            for (int g = 0; g < 4; ++g) {
                float w = Whh[(size_t)(g * 256 + tid) * 256 + k];
                #pragma unroll
                for (int rr = 0; rr < 4; ++rr) acc[g][rr] += w * hv[rr];
            }
        }
        __syncthreads();
        #pragma unroll
        for (int rr = 0; rr < 4; ++rr) {
            float iv = 1.0f / (1.0f + expf(-acc[0][rr]));
            float fv = 1.0f / (1.0f + expf(-acc[1][rr]));
            float gv = tanhf(acc[2][rr]);
            float ov = 1.0f / (1.0f + expf(-acc[3][rr]));
            float cn = fv * c[rr] + iv * gv;
            c[rr] = cn;
            sm.h[rr][tid] = ov * tanhf(cn);
        }
        __syncthreads();
        { int col = tid & 127, rb = (tid >> 7) * 2;
          float a0 = b1[col], a1 = a0;
          for (int k = 0; k < 256; ++k) { float w = W1[(size_t)col * 256 + k];
              a0 += w * sm.h[rb][k]; a1 += w * sm.h[rb + 1][k]; }
          sm.u1[rb][col] = fmaxf(a0, 0.0f); sm.u1[rb + 1][col] = fmaxf(a1, 0.0f); }
        __syncthreads();
        { int col = tid & 127, rb = (tid >> 7) * 2;
          float a0 = b2[col], a1 = a0;
          for (int k = 0; k < 128; ++k) { float w = W2[(size_t)col * 128 + k];
              a0 += w * sm.u1[rb][k]; a1 += w * sm.u1[rb + 1][k]; }
          sm.u2[rb][col] = fmaxf(a0, 0.0f); sm.u2[rb + 1][col] = fmaxf(a1, 0.0f); }
        __syncthreads();
        { int rr = tid >> 6, col = tid & 63;
          float a0 = bz[col];
          for (int k = 0; k < 128; ++k) a0 += Wz[(size_t)col * 128 + k] * sm.u2[rr][k];
          sm.zz[rr][col] = a0; }
        __syncthreads();
        if (tid < 128) {
            int rr = tid >> 5, cc = tid & 31;
            float loc = sm.zz[rr][cc], raw = sm.zz[rr][cc + 32];
            float sp  = (raw > 20.0f) ? raw : log1pf(expf(raw));
            float ev  = eps[((size_t)(n0 + rr) * T_LEN + t) * 32 + cc];
            float zv  = loc + sp * ev;
            sm.zx[rr][8 + cc] = zv;
            out[((size_t)(n0 + rr) * T_LEN + t) * 32 + cc] = zv;
        }
        __syncthreads();
    }
}

extern "C" void kernel_launch(void* const* d_in, const int* in_sizes, int n_in,
                              void* d_out, int out_size, void* d_ws, size_t ws_size,
                              hipStream_t stream)
{
    const float* A   = (const float*)d_in[0];
    const float* eps = (const float*)d_in[1];
    const float* z0  = (const float*)d_in[2];
    const float* h0  = (const float*)d_in[3];
    const float* c0  = (const float*)d_in[4];
    const float* Wih = (const float*)d_in[5];
    const float* Whh = (const float*)d_in[6];
    const float* bih = (const float*)d_in[7];
    const float* bhh = (const float*)d_in[8];
    const float* W1  = (const float*)d_in[9];
    const float* b1  = (const float*)d_in[10];
    const float* W2  = (const float*)d_in[11];
    const float* b2  = (const float*)d_in[12];
    const float* Wz  = (const float*)d_in[13];
    const float* bz  = (const float*)d_in[14];
    float* out = (float*)d_out;

    if (ws_size >= WS_NEEDED) {
        prep_kernel<<<188, 256, 0, stream>>>(Wih, Whh, W1, W2, Wz, (unsigned char*)d_ws);
        seq_mfma<<<64, 512, 0, stream>>>(A, eps, z0, h0, c0,
                                         bih, bhh, b1, b2, bz,
                                         (const unsigned char*)d_ws, out);
    } else {
        seq_valu<<<256, 256, 0, stream>>>(A, eps, z0, h0, c0, Wih, Whh, bih, bhh,
                                          W1, b1, W2, b2, Wz, bz, out);
    }
}

// Round 12
// 1525.708 us; speedup vs baseline: 1.2270x; 1.0412x over previous
//
#include <hip/hip_runtime.h>
#include <hip/hip_bf16.h>
#include <math.h>

typedef __bf16 bf16x8 __attribute__((ext_vector_type(8)));
typedef float floatx4 __attribute__((ext_vector_type(4)));

#define T_LEN 128

// ws layout: bf16 fragment-packed weights, gates KI-MAJOR:
//   gate frag addr = WP_OFF + ki*65536 + ct*1024 + lane*16
// K order: [ a(8) | z(32) | h(256) | pad(24) ]   (R8's verified layout)
#define WP_OFF   0
#define WP_SZ    (64*10*64*16)     // 655360
#define W1P_OFF  (WP_OFF + WP_SZ)
#define W1P_SZ   (8*8*64*16)       // 65536
#define W2P_OFF  (W1P_OFF + W1P_SZ)
#define W2P_SZ   (8*4*64*16)       // 32768
#define WZP_OFF  (W2P_OFF + W2P_SZ)
#define WZP_SZ   (4*4*64*16)       // 16384
#define WS_NEEDED ((size_t)(WZP_OFF + WZP_SZ))   // 770048 B

// s_waitcnt imm: wait until <=N vmem outstanding (expcnt/lgkmcnt don't care)
#define WAITVM(N) (((N) & 0xF) | (0x7 << 4) | (0xF << 8) | (((N) >> 4) << 14))

// raw barrier: LDS writes visible, VMEM (DMA) loads STAY IN FLIGHT
#define BAR() do {                                                  \
    asm volatile("s_waitcnt lgkmcnt(0)" ::: "memory");              \
    __builtin_amdgcn_sched_barrier(0);                              \
    __builtin_amdgcn_s_barrier();                                   \
    __builtin_amdgcn_sched_barrier(0);                              \
} while (0)

#define WAITN(N) do { __builtin_amdgcn_s_waitcnt(WAITVM(N)); \
    __builtin_amdgcn_sched_barrier(0); } while (0)

// ---- fast transcendentals ------------------------------------------------
#if __has_builtin(__builtin_amdgcn_exp2f)
#define EXP2F(x) __builtin_amdgcn_exp2f(x)
#else
#define EXP2F(x) exp2f(x)
#endif
#if __has_builtin(__builtin_amdgcn_logf)
#define LOG2F(x) __builtin_amdgcn_logf(x)
#else
#define LOG2F(x) log2f(x)
#endif
#if __has_builtin(__builtin_amdgcn_rcpf)
#define RCPF(x) __builtin_amdgcn_rcpf(x)
#else
#define RCPF(x) (1.0f/(x))
#endif

__device__ __forceinline__ float fsigmoid(float x) {
    return RCPF(1.0f + EXP2F(-1.4426950408889634f * x));
}
__device__ __forceinline__ float ftanh(float x) {
    return 1.0f - 2.0f * RCPF(1.0f + EXP2F(2.8853900817779268f * x));
}

// async 16B/lane global->LDS DMA; LDS base wave-uniform, lands at +lane*16
__device__ __forceinline__ void dma16(const void* g, void* lds) {
    __builtin_amdgcn_global_load_lds(
        (const __attribute__((address_space(1))) void*)g,
        (__attribute__((address_space(3))) void*)lds,
        16, 0, 0);
}

// ---------------- prep: f32 weights -> bf16 B-fragment-linear in ws -------
__global__ void prep_kernel(const float* __restrict__ Wih, const float* __restrict__ Whh,
                            const float* __restrict__ W1,  const float* __restrict__ W2,
                            const float* __restrict__ Wz,  unsigned char* __restrict__ ws)
{
    int id = blockIdx.x * blockDim.x + threadIdx.x;
    __bf16* Wp  = (__bf16*)(ws + WP_OFF);
    __bf16* W1p = (__bf16*)(ws + W1P_OFF);
    __bf16* W2p = (__bf16*)(ws + W2P_OFF);
    __bf16* Wzp = (__bf16*)(ws + WZP_OFF);
    if (id < 40960) {                       // gates: 64 ct x 10 ki x 64 lanes
        int ct = id / 640, rem = id % 640;
        int ki = rem / 64, lane = rem % 64;
        int row = ct * 16 + (lane & 15);                 // gate-output col
        int kb  = ki * 32 + (lane >> 4) * 8;
        for (int j = 0; j < 8; ++j) {
            int k = kb + j;
            float v;
            if (k < 40)       v = Wih[row * 40 + k];     // [a|z] = Wih cols
            else if (k < 296) v = Whh[row * 256 + (k - 40)];
            else              v = 0.0f;                   // pad 296..319
            Wp[((size_t)(ki * 64 + ct) * 64 + lane) * 8 + j] = (__bf16)v;
        }
    } else if (id < 45056) {                // W1: 8 ct x 8 ki (ct-major)
        int id2 = id - 40960;
        int rem = id2 % 512, lane = rem % 64;
        int row = (id2 / 512) * 16 + (lane & 15);
        int kb  = (rem / 64) * 32 + (lane >> 4) * 8;
        for (int j = 0; j < 8; ++j) W1p[(size_t)id2 * 8 + j] = (__bf16)W1[row * 256 + kb + j];
    } else if (id < 47104) {                // W2: 8 ct x 4 ki
        int id3 = id - 45056;
        int rem = id3 % 256, lane = rem % 64;
        int row = (id3 / 256) * 16 + (lane & 15);
        int kb  = (rem / 64) * 32 + (lane >> 4) * 8;
        for (int j = 0; j < 8; ++j) W2p[(size_t)id3 * 8 + j] = (__bf16)W2[row * 128 + kb + j];
    } else if (id < 48128) {                // Wz: 4 ct x 4 ki
        int id4 = id - 47104;
        int rem = id4 % 256, lane = rem % 64;
        int row = (id4 / 256) * 16 + (lane & 15);
        int kb  = (rem / 64) * 32 + (lane >> 4) * 8;
        for (int j = 0; j < 8; ++j) Wzp[(size_t)id4 * 8 + j] = (__bf16)Wz[row * 128 + kb + j];
    }
}

// ---------------- fast path: 64 blocks x 512 threads (8 waves) ------------
// R12 = R8 skeleton with FULL-KI ring units (8 KB/wave, 8 ops) at depth 2.
//  * 10 waits/step in the gate stream instead of 20 -> halves latency
//    exposure; per-unit work (8 MFMA + 8 dma) partially covers L2 latency.
//  * W2/Wz stream through the ring as unit #11 (prefetched at ki8-consume,
//    consumed in u2/zz phases across 2-3 barriers of slack -> never stalls).
//    Frees their 48 KB LDS residency to pay for the 128 KB ring.
//  * 11 units/step (odd) -> runtime slot-base toggle sb ^= 1 per step
//    (scalar arithmetic, single-step body, NO unroll -> I-cache safe).
//  * vmcnt (never drained; robust to store-counting ambiguity):
//    k0,k1: wait(9); k2..k9: wait(8); W2: wait(12); Wz: wait(8).
//  * Wz wait is UNCONDITIONAL so the k1' refill can't overwrite an
//    in-flight W2Wz slab (waves 4-7 never read Wz but share the slot).
__global__ __launch_bounds__(512) void seq_mfma(
    const float* __restrict__ A,   const float* __restrict__ eps,
    const float* __restrict__ z0,  const float* __restrict__ h0,
    const float* __restrict__ c0,
    const float* __restrict__ bih, const float* __restrict__ bhh,
    const float* __restrict__ b1,  const float* __restrict__ b2,
    const float* __restrict__ bz,
    const unsigned char* __restrict__ ws, float* __restrict__ out)
{
    const int tid  = threadIdx.x;
    const int w    = tid >> 6;          // wave 0..7
    const int lane = tid & 63;
    const int lrow = lane & 15;
    const int quad = lane >> 4;
    const int n0   = blockIdx.x * 16;

    __shared__ __align__(16) __bf16 slots[8][2][4096];   // 128 KB full-ki ring
    __shared__ __align__(16) __bf16 xh[2][16][328];      // [a|z|h|pad] 20.5 KB
    __shared__ __align__(16) __bf16 u1s[16][136];        // + zz f32 overlay
    __shared__ __align__(16) __bf16 u2s[16][136];
    float* zzf = (float*)&u1s[0][0];                     // [16][68] f32 view

    const char* wsb = (const char*)ws;

    // init both xh buffers: a(0)=0 | z0 | h0 | pad 0
    for (int idx = tid; idx < 2 * 16 * 320; idx += 512) {
        int b = idx / (16 * 320);
        int rem = idx % (16 * 320);
        int r = rem / 320, col = rem % 320;
        float v;
        if (col >= 8 && col < 40)        v = z0[col - 8];
        else if (col >= 40 && col < 296) v = h0[col - 40];
        else                             v = 0.0f;
        xh[b][r][col] = (__bf16)v;
    }
    if (tid < 128)   // a(t=0)
        xh[0][tid >> 3][tid & 7] =
            (__bf16)A[((size_t)(n0 + (tid >> 3)) * T_LEN + 0) * 8 + (tid & 7)];

    // W1 VGPR-resident (ct = w): 32 regs
    bf16x8 w1f[8];
    #pragma unroll
    for (int k = 0; k < 8; ++k)
        w1f[k] = *(const bf16x8*)(wsb + W1P_OFF + ((size_t)(w * 8 + k) * 64 + lane) * 16);

    // biases & recurrent state (R8-proven mapping)
    float gb[4][2];
    #pragma unroll
    for (int g = 0; g < 4; ++g)
        #pragma unroll
        for (int j = 0; j < 2; ++j) {
            int unit = 32 * w + 16 * j + lrow;
            gb[g][j] = bih[g * 256 + unit] + bhh[g * 256 + unit];
        }
    float u1b = b1[w * 16 + lrow];
    float u2b = b2[w * 16 + lrow];
    float zzb = (w < 4) ? bz[w * 16 + lrow] : 0.0f;
    float cst[2][4];
    #pragma unroll
    for (int j = 0; j < 2; ++j) {
        float cv = c0[32 * w + 16 * j + lrow];
        #pragma unroll
        for (int r = 0; r < 4; ++r) cst[j][r] = cv;
    }

    // ---- ring macros (compile-time ki, RUNTIME slot pointer) ----
    // slot layout: frag (G,j) at (G*2+j)*512 bf16; ct = G*16 + 2w + j
    #define DMAKI(KI, SP) do {                                                \
        _Pragma("unroll")                                                     \
        for (int G = 0; G < 4; ++G)                                           \
            _Pragma("unroll")                                                 \
            for (int j = 0; j < 2; ++j)                                       \
                dma16(wsb + WP_OFF + (size_t)(KI) * 65536 +                   \
                      ((size_t)(G * 16 + 2 * w + j) * 1024) +                 \
                      (size_t)lane * 16,                                      \
                      (void*)((SP) + (G * 2 + j) * 512));                     \
    } while (0)
    // W2 (4 frags, ct=w) at 0..3*512 ; Wz (4 frags, ct=w&3) at 4..7*512
    #define DMAMX(SP) do {                                                    \
        _Pragma("unroll")                                                     \
        for (int i = 0; i < 4; ++i)                                           \
            dma16(wsb + W2P_OFF + (size_t)w * 4096 + (size_t)i * 1024 +       \
                  (size_t)lane * 16, (void*)((SP) + i * 512));                \
        _Pragma("unroll")                                                     \
        for (int i = 0; i < 4; ++i)                                           \
            dma16(wsb + WZP_OFF + (size_t)(w & 3) * 4096 + (size_t)i * 1024 + \
                  (size_t)lane * 16, (void*)((SP) + (4 + i) * 512));          \
    } while (0)
    #define CONSKI(KI, SP, WN) do {                                           \
        bf16x8 af = *(const bf16x8*)&xh[cb][lrow][(KI) * 32 + quad * 8];      \
        WAITN(WN);                                                            \
        _Pragma("unroll")                                                     \
        for (int G = 0; G < 4; ++G)                                           \
            _Pragma("unroll")                                                 \
            for (int j = 0; j < 2; ++j) {                                     \
                bf16x8 b_ = *(const bf16x8*)((SP) + (G * 2 + j) * 512         \
                                             + lane * 8);                     \
                acc[G][j] = __builtin_amdgcn_mfma_f32_16x16x32_bf16(          \
                    af, b_, acc[G][j], 0, 0, 0);                              \
            }                                                                 \
        __builtin_amdgcn_sched_barrier(0);                                    \
    } while (0)

    __bf16* const sbase = &slots[w][0][0];
    int sb = 0;   // runtime slot-base parity (flips each step: 11 units/step)

    // prologue: k0 -> slot0, k1 -> slot1; syncthreads drains them
    DMAKI(0, sbase);
    DMAKI(1, sbase + 4096);
    __syncthreads();

    for (int t = 0; t < T_LEN; ++t) {
        const int cb = t & 1;        // X_t = [a(t) | z(t-1) | h(t-1)]
        const int nb = cb ^ 1;       // receives h(t), a(t+1), z(t)

        __bf16* const s0 = sbase + sb * 4096;          // even units this step
        __bf16* const s1 = sbase + (sb ^ 1) * 4096;    // odd units this step

        // eps(t)/a(t+1) issued at step top (oldest in queue; retire early)
        float eps_cur = eps[((size_t)(n0 + (tid >> 5)) * T_LEN + t) * 32 + (tid & 31)];
        float a_nxt = 0.0f;
        if (t + 1 < T_LEN && tid < 128)
            a_nxt = A[((size_t)(n0 + (tid >> 3)) * T_LEN + (t + 1)) * 8 + (tid & 7)];

        // ---- gates: 10 full-ki units; consume u -> refill u+2 (same slot)
        floatx4 acc[4][2];
        #pragma unroll
        for (int g = 0; g < 4; ++g)
            #pragma unroll
            for (int j = 0; j < 2; ++j)
                acc[g][j] = (floatx4){gb[g][j], gb[g][j], gb[g][j], gb[g][j]};

        CONSKI(0, s0, 9);   DMAKI(2, s0);
        CONSKI(1, s1, 9);   DMAKI(3, s1);
        CONSKI(2, s0, 8);   DMAKI(4, s0);
        CONSKI(3, s1, 8);   DMAKI(5, s1);
        CONSKI(4, s0, 8);   DMAKI(6, s0);
        CONSKI(5, s1, 8);   DMAKI(7, s1);
        CONSKI(6, s0, 8);   DMAKI(8, s0);
        CONSKI(7, s1, 8);   DMAKI(9, s1);
        CONSKI(8, s0, 8);   DMAMX(s0);      // W2|Wz for this step's MLP
        CONSKI(9, s1, 8);   DMAKI(0, s1);   // next-step k0 (long slack)

        // ---- LSTM cell (own acc only) -> h(t) into X_{t+1}
        #pragma unroll
        for (int j = 0; j < 2; ++j)
            #pragma unroll
            for (int r = 0; r < 4; ++r) {
                float iv = fsigmoid(acc[0][j][r]);
                float fv = fsigmoid(acc[1][j][r]);
                float gv = ftanh(acc[2][j][r]);
                float ov = fsigmoid(acc[3][j][r]);
                float cn = fv * cst[j][r] + iv * gv;
                cst[j][r] = cn;
                xh[nb][quad * 4 + r][40 + 32 * w + 16 * j + lrow] = (__bf16)(ov * ftanh(cn));
            }
        if (t + 1 < T_LEN && tid < 128)
            xh[nb][tid >> 3][tid & 7] = (__bf16)a_nxt;
        BAR();   // B2: h(t) + a(t+1) staged (DMA stays in flight)

        // ---- u1 = relu(h @ W1^T + b1): W1 VGPR-resident, ds-only
        {
            floatx4 a1 = (floatx4){u1b, u1b, u1b, u1b};
            #pragma unroll
            for (int ki = 0; ki < 8; ++ki) {
                bf16x8 af1 = *(const bf16x8*)&xh[nb][lrow][40 + ki * 32 + quad * 8];
                a1 = __builtin_amdgcn_mfma_f32_16x16x32_bf16(af1, w1f[ki], a1, 0, 0, 0);
            }
            #pragma unroll
            for (int r = 0; r < 4; ++r)
                u1s[quad * 4 + r][w * 16 + lrow] = (__bf16)fmaxf(a1[r], 0.0f);
        }
        BAR();   // B3: u1s ready

        // ---- u2 = relu(u1 @ W2^T + b2): W2 = first half of W2Wz slab (s0)
        {
            WAITN(12);   // W2 landed (Wz(4) + k0'(8) newer)
            floatx4 a2 = (floatx4){u2b, u2b, u2b, u2b};
            #pragma unroll
            for (int ki = 0; ki < 4; ++ki) {
                bf16x8 af2 = *(const bf16x8*)&u1s[lrow][ki * 32 + quad * 8];
                bf16x8 bb  = *(const bf16x8*)(s0 + ki * 512 + lane * 8);
                a2 = __builtin_amdgcn_mfma_f32_16x16x32_bf16(af2, bb, a2, 0, 0, 0);
            }
            #pragma unroll
            for (int r = 0; r < 4; ++r)
                u2s[quad * 4 + r][w * 16 + lrow] = (__bf16)fmaxf(a2[r], 0.0f);
        }
        BAR();   // B4: u2s ready (u1s free for zz overlay)

        // ---- zz = u2 @ Wz^T + bz: Wz = second half of W2Wz slab (s0)
        WAITN(8);   // UNCONDITIONAL: Wz landed (k0'(8) newer) — also makes
                    // the k1' refill below safe (no in-flight writes to s0)
        if (w < 4) {
            floatx4 a3 = (floatx4){zzb, zzb, zzb, zzb};
            #pragma unroll
            for (int ki = 0; ki < 4; ++ki) {
                bf16x8 af3 = *(const bf16x8*)&u2s[lrow][ki * 32 + quad * 8];
                bf16x8 bb  = *(const bf16x8*)(s0 + (4 + ki) * 512 + lane * 8);
                a3 = __builtin_amdgcn_mfma_f32_16x16x32_bf16(af3, bb, a3, 0, 0, 0);
            }
            #pragma unroll
            for (int r = 0; r < 4; ++r)
                zzf[(quad * 4 + r) * 68 + w * 16 + lrow] = a3[r];
        }
        __builtin_amdgcn_sched_barrier(0);
        DMAKI(1, s0);   // next-step k1 into the consumed W2Wz slot
        BAR();   // B5: zz ready

        // ---- z = loc + softplus(raw)*eps -> X_{t+1}.z + out
        {
            int r = tid >> 5, c = tid & 31;
            float loc = zzf[r * 68 + c];
            float raw = zzf[r * 68 + c + 32];
            float sp  = (raw > 20.0f)
                      ? raw
                      : 0.6931471805599453f *
                        LOG2F(1.0f + EXP2F(1.4426950408889634f * raw));
            float zv  = loc + sp * eps_cur;
            xh[nb][r][8 + c] = (__bf16)zv;
            out[((size_t)(n0 + r) * T_LEN + t) * 32 + c] = zv;
        }
        BAR();   // B1: X_{t+1} complete for next step
        sb ^= 1;
    }
    #undef CONSKI
    #undef DMAMX
    #undef DMAKI
}

// ---------------- fallback: proven R4 VALU kernel (f32 hard-coded) --------
struct SM {
    float zx[4][40]; float h[4][256]; float u1[4][128]; float u2[4][128]; float zz[4][64];
};

__global__ __launch_bounds__(256) void seq_valu(
    const float* __restrict__ A, const float* __restrict__ eps,
    const float* __restrict__ z0, const float* __restrict__ h0, const float* __restrict__ c0,
    const float* __restrict__ Wih, const float* __restrict__ Whh,
    const float* __restrict__ bih, const float* __restrict__ bhh,
    const float* __restrict__ W1, const float* __restrict__ b1,
    const float* __restrict__ W2, const float* __restrict__ b2,
    const float* __restrict__ Wz, const float* __restrict__ bz, float* __restrict__ out)
{
    __shared__ SM sm;
    const int tid = threadIdx.x;
    const int n0  = blockIdx.x * 4;
    if (tid < 128) { int rr = tid >> 5, cc = tid & 31; sm.zx[rr][8 + cc] = z0[cc]; }
    for (int i = tid; i < 4 * 256; i += 256) sm.h[i >> 8][i & 255] = h0[i & 255];
    float c[4];
    #pragma unroll
    for (int rr = 0; rr < 4; ++rr) c[rr] = c0[tid];
    float gbias[4];
    #pragma unroll
    for (int g = 0; g < 4; ++g) gbias[g] = bih[g * 256 + tid] + bhh[g * 256 + tid];

    for (int t = 0; t < T_LEN; ++t) {
        if (tid < 32) { int rr = tid >> 3, cc = tid & 7;
            sm.zx[rr][cc] = A[((size_t)(n0 + rr) * T_LEN + t) * 8 + cc]; }
        __syncthreads();
        float acc[4][4];
        #pragma unroll
        for (int g = 0; g < 4; ++g)
            #pragma unroll
            for (int rr = 0; rr < 4; ++rr) acc[g][rr] = gbias[g];
        for (int k = 0; k < 40; ++k) {
            float xv[4];
            #pragma unroll
            for (int rr = 0; rr < 4; ++rr) xv[rr] = sm.zx[rr][k];
            #pragma unroll
            for (int g = 0; g < 4; ++g) {
                float w = Wih[(size_t)(g * 256 + tid) * 40 + k];
                #pragma unroll
                for (int rr = 0; rr < 4; ++rr) acc[g][rr] += w * xv[rr];
            }
        }
        for (int k = 0; k < 256; ++k) {
            float hv[4];
            #pragma unroll
            for (int rr = 0; rr < 4; ++rr) hv[rr] = sm.h[rr][k];
            #pragma unroll
            for (int g = 0; g < 4; ++g) {
                float w = Whh[(size_t)(g * 256 + tid) * 256 + k];
                #pragma unroll
                for (int rr = 0; rr < 4; ++rr) acc[g][rr] += w * hv[rr];
            }
        }
        __syncthreads();
        #pragma unroll
        for (int rr = 0; rr < 4; ++rr) {
            float iv = 1.0f / (1.0f + expf(-acc[0][rr]));
            float fv = 1.0f / (1.0f + expf(-acc[1][rr]));
            float gv = tanhf(acc[2][rr]);
            float ov = 1.0f / (1.0f + expf(-acc[3][rr]));
            float cn = fv * c[rr] + iv * gv;
            c[rr] = cn;
            sm.h[rr][tid] = ov * tanhf(cn);
        }
        __syncthreads();
        { int col = tid & 127, rb = (tid >> 7) * 2;
          float a0 = b1[col], a1 = a0;
          for (int k = 0; k < 256; ++k) { float w = W1[(size_t)col * 256 + k];
              a0 += w * sm.h[rb][k]; a1 += w * sm.h[rb + 1][k]; }
          sm.u1[rb][col] = fmaxf(a0, 0.0f); sm.u1[rb + 1][col] = fmaxf(a1, 0.0f); }
        __syncthreads();
        { int col = tid & 127, rb = (tid >> 7) * 2;
          float a0 = b2[col], a1 = a0;
          for (int k = 0; k < 128; ++k) { float w = W2[(size_t)col * 128 + k];
              a0 += w * sm.u1[rb][k]; a1 += w * sm.u1[rb + 1][k]; }
          sm.u2[rb][col] = fmaxf(a0, 0.0f); sm.u2[rb + 1][col] = fmaxf(a1, 0.0f); }
        __syncthreads();
        { int rr = tid >> 6, col = tid & 63;
          float a0 = bz[col];
          for (int k = 0; k < 128; ++k) a0 += Wz[(size_t)col * 128 + k] * sm.u2[rr][k];
          sm.zz[rr][col] = a0; }
        __syncthreads();
        if (tid < 128) {
            int rr = tid >> 5, cc = tid & 31;
            float loc = sm.zz[rr][cc], raw = sm.zz[rr][cc + 32];
            float sp  = (raw > 20.0f) ? raw : log1pf(expf(raw));
            float ev  = eps[((size_t)(n0 + rr) * T_LEN + t) * 32 + cc];
            float zv  = loc + sp * ev;
            sm.zx[rr][8 + cc] = zv;
            out[((size_t)(n0 + rr) * T_LEN + t) * 32 + cc] = zv;
        }
        __syncthreads();
    }
}

extern "C" void kernel_launch(void* const* d_in, const int* in_sizes, int n_in,
                              void* d_out, int out_size, void* d_ws, size_t ws_size,
                              hipStream_t stream)
{
    const float* A   = (const float*)d_in[0];
    const float* eps = (const float*)d_in[1];
    const float* z0  = (const float*)d_in[2];
    const float* h0  = (const float*)d_in[3];
    const float* c0  = (const float*)d_in[4];
    const float* Wih = (const float*)d_in[5];
    const float* Whh = (const float*)d_in[6];
    const float* bih = (const float*)d_in[7];
    const float* bhh = (const float*)d_in[8];
    const float* W1  = (const float*)d_in[9];
    const float* b1  = (const float*)d_in[10];
    const float* W2  = (const float*)d_in[11];
    const float* b2  = (const float*)d_in[12];
    const float* Wz  = (const float*)d_in[13];
    const float* bz  = (const float*)d_in[14];
    float* out = (float*)d_out;

    if (ws_size >= WS_NEEDED) {
        prep_kernel<<<188, 256, 0, stream>>>(Wih, Whh, W1, W2, Wz, (unsigned char*)d_ws);
        seq_mfma<<<64, 512, 0, stream>>>(A, eps, z0, h0, c0,
                                         bih, bhh, b1, b2, bz,
                                         (const unsigned char*)d_ws, out);
    } else {
        seq_valu<<<256, 256, 0, stream>>>(A, eps, z0, h0, c0, Wih, Whh, bih, bhh,
                                          W1, b1, W2, b2, Wz, bz, out);
    }
}